// Round 1
// baseline (1552.133 us; speedup 1.0000x reference)
//
#include <hip/hip_runtime.h>
#include <math.h>

// Problem constants (B,T,D,H fixed by the reference)
#define Bc  4
#define Tc  1024
#define Dc  512
#define Hc  8
#define DKc 64
#define Pc  2047   // 2T-1
#define QB  8      // q rows per attention block

// ---------------------------------------------------------------------------
// GEMM: C[M,N] = A[M,K] @ W[N,K]^T + bias   (bias may be nullptr)
// 64x64 tile, BK=32, 256 threads, 4x4 micro-tile per thread.
// ---------------------------------------------------------------------------
__global__ __launch_bounds__(256)
void gemm_awt(const float* __restrict__ A, const float* __restrict__ W,
              const float* __restrict__ bias, float* __restrict__ C,
              int M, int N, int K)
{
    __shared__ float As[64][33];   // +1 pad: kill bank conflicts
    __shared__ float Ws[64][33];

    const int bm  = blockIdx.y * 64;
    const int bn  = blockIdx.x * 64;
    const int tid = threadIdx.x;
    const int tx  = tid & 15;      // 16 cols of threads
    const int ty  = tid >> 4;      // 16 rows of threads

    float acc[4][4] = {};

    for (int k0 = 0; k0 < K; k0 += 32) {
        // stage A tile (64x32) and W tile (64x32); A rows may be out of range (M=2047)
        for (int i = tid; i < 64 * 32; i += 256) {
            int r = i >> 5, c = i & 31;
            int m = bm + r;
            As[r][c] = (m < M) ? A[(size_t)m * K + k0 + c] : 0.f;
        }
        for (int i = tid; i < 64 * 32; i += 256) {
            int r = i >> 5, c = i & 31;
            Ws[r][c] = W[(size_t)(bn + r) * K + k0 + c];   // N=512, always in range
        }
        __syncthreads();

        #pragma unroll
        for (int kk = 0; kk < 32; ++kk) {
            float a[4], b[4];
            #pragma unroll
            for (int i = 0; i < 4; ++i) a[i] = As[ty * 4 + i][kk];
            #pragma unroll
            for (int j = 0; j < 4; ++j) b[j] = Ws[tx * 4 + j][kk];
            #pragma unroll
            for (int i = 0; i < 4; ++i)
                #pragma unroll
                for (int j = 0; j < 4; ++j)
                    acc[i][j] += a[i] * b[j];
        }
        __syncthreads();
    }

    #pragma unroll
    for (int i = 0; i < 4; ++i) {
        int m = bm + ty * 4 + i;
        if (m >= M) continue;
        #pragma unroll
        for (int j = 0; j < 4; ++j) {
            int n = bn + tx * 4 + j;
            float v = acc[i][j];
            if (bias) v += bias[n];
            C[(size_t)m * N + n] = v;
        }
    }
}

// ---------------------------------------------------------------------------
// Wave-64 reductions
// ---------------------------------------------------------------------------
__device__ __forceinline__ float wave_max64(float v) {
    #pragma unroll
    for (int off = 32; off > 0; off >>= 1)
        v = fmaxf(v, __shfl_xor(v, off, 64));
    return v;
}
__device__ __forceinline__ float wave_sum64(float v) {
    #pragma unroll
    for (int off = 32; off > 0; off >>= 1)
        v += __shfl_xor(v, off, 64);
    return v;
}

// ---------------------------------------------------------------------------
// Fused relative-position attention.
// One block = one (b, h, q-tile of 8 rows).
//   scores[qi][k] = (qh[q]+u)·kh[k] + (qh[q]+v)·ph[k - q + T-1]
//   softmax(scores/8) ; out = P @ V
// rel_shift is folded into the BD index: out[q,k] = bd[q, T-1+k-q].
// BD phase iterates the 1031 needed pos rows ONCE each; for row index
// rr (rbase = T-1-(q0+7)):  k = rr - 7 + qi  (independent of q0).
// ---------------------------------------------------------------------------
__global__ __launch_bounds__(256)
void relattn(const float* __restrict__ qh, const float* __restrict__ kh,
             const float* __restrict__ vh, const float* __restrict__ ph,
             const float* __restrict__ pbu, const float* __restrict__ pbv,
             float* __restrict__ ao)
{
    __shared__ float s_sc[QB][Tc];          // 32 KB score tile
    __shared__ float s_qu[QB][DKc];         // q + pos_bias_u
    __shared__ float s_qv[QB][DKc];         // q + pos_bias_v
    __shared__ float s_red[8];
    __shared__ float s_inv[QB];
    __shared__ float s_part[4][QB][DKc];    // PV partials (8 KB)

    const int tid = threadIdx.x;
    const int bid = blockIdx.x;
    const int qt  = bid & (Tc / QB - 1);    // 128 q-tiles
    const int h   = (bid >> 7) & (Hc - 1);
    const int b   = bid >> 10;
    const int q0  = qt * QB;

    // ---- load 8 q rows, add u/v biases ----
    for (int i = tid; i < QB * DKc; i += 256) {
        int qi = i >> 6, d = i & 63;
        float x = qh[((size_t)(b * Tc + q0 + qi)) * Dc + h * DKc + d];
        s_qu[qi][d] = x + pbu[h * DKc + d];
        s_qv[qi][d] = x + pbv[h * DKc + d];
    }
    __syncthreads();

    // ---- AC: content scores; each kh row read once per block ----
    for (int k = tid; k < Tc; k += 256) {
        const float4* kr = (const float4*)(kh + ((size_t)(b * Tc + k)) * Dc + h * DKc);
        float acc[QB] = {};
        #pragma unroll
        for (int d4 = 0; d4 < 16; ++d4) {
            float4 kv = kr[d4];
            #pragma unroll
            for (int qi = 0; qi < QB; ++qi) {
                float4 qv = ((const float4*)s_qu[qi])[d4];   // LDS broadcast
                acc[qi] += qv.x * kv.x + qv.y * kv.y + qv.z * kv.z + qv.w * kv.w;
            }
        }
        #pragma unroll
        for (int qi = 0; qi < QB; ++qi) s_sc[qi][k] = acc[qi];
    }
    __syncthreads();

    // ---- BD: positional scores; each needed ph row read once per block ----
    const int rbase = (Tc - 1) - (q0 + QB - 1);
    for (int rr = tid; rr < Tc + QB - 1; rr += 256) {
        const float4* pr = (const float4*)(ph + (size_t)(rbase + rr) * Dc + h * DKc);
        float acc[QB] = {};
        #pragma unroll
        for (int d4 = 0; d4 < 16; ++d4) {
            float4 pv = pr[d4];
            #pragma unroll
            for (int qi = 0; qi < QB; ++qi) {
                float4 qv = ((const float4*)s_qv[qi])[d4];
                acc[qi] += qv.x * pv.x + qv.y * pv.y + qv.z * pv.z + qv.w * pv.w;
            }
        }
        #pragma unroll
        for (int qi = 0; qi < QB; ++qi) {
            int k = rr - (QB - 1) + qi;
            if ((unsigned)k < (unsigned)Tc) s_sc[qi][k] += acc[qi];
        }
    }
    __syncthreads();

    // ---- softmax over k, scale 1/sqrt(64)=0.125 applied inside exp ----
    for (int qi = 0; qi < QB; ++qi) {
        float m = -1e30f;
        for (int k = tid; k < Tc; k += 256) m = fmaxf(m, s_sc[qi][k]);
        m = wave_max64(m);
        if ((tid & 63) == 0) s_red[tid >> 6] = m;
        __syncthreads();
        m = fmaxf(fmaxf(s_red[0], s_red[1]), fmaxf(s_red[2], s_red[3]));

        float sum = 0.f;
        for (int k = tid; k < Tc; k += 256) {
            float e = __expf((s_sc[qi][k] - m) * 0.125f);
            s_sc[qi][k] = e;
            sum += e;
        }
        sum = wave_sum64(sum);
        __syncthreads();                          // s_red reads above complete
        if ((tid & 63) == 0) s_red[tid >> 6] = sum;
        __syncthreads();
        if (tid == 0) s_inv[qi] = 1.f / (s_red[0] + s_red[1] + s_red[2] + s_red[3]);
        __syncthreads();                          // protect s_red for next row
    }

    // ---- PV: each vh row read once; v value reused across 8 q rows ----
    const int d  = tid & 63;
    const int wv = tid >> 6;                      // k-chunk = wave id
    float acc[QB] = {};
    for (int kk = 0; kk < Tc / 4; ++kk) {
        int k = wv * (Tc / 4) + kk;
        float vval = vh[((size_t)(b * Tc + k)) * Dc + h * DKc + d];
        #pragma unroll
        for (int qi = 0; qi < QB; ++qi) acc[qi] += s_sc[qi][k] * vval;  // broadcast
    }
    #pragma unroll
    for (int qi = 0; qi < QB; ++qi) s_part[wv][qi][d] = acc[qi];
    __syncthreads();

    for (int i = tid; i < QB * DKc; i += 256) {
        int qi = i >> 6, dd = i & 63;
        float s = (s_part[0][qi][dd] + s_part[1][qi][dd] +
                   s_part[2][qi][dd] + s_part[3][qi][dd]) * s_inv[qi];
        ao[((size_t)(b * Tc + q0 + qi)) * Dc + h * DKc + dd] = s;
    }
}

// ---------------------------------------------------------------------------
extern "C" void kernel_launch(void* const* d_in, const int* in_sizes, int n_in,
                              void* d_out, int out_size, void* d_ws, size_t ws_size,
                              hipStream_t stream)
{
    const float* q   = (const float*)d_in[0];
    const float* k   = (const float*)d_in[1];
    const float* v   = (const float*)d_in[2];
    const float* pe  = (const float*)d_in[3];   // (1,P,D) -> (P,D)
    const float* Wq  = (const float*)d_in[4];
    const float* bq  = (const float*)d_in[5];
    const float* Wk  = (const float*)d_in[6];
    const float* bk  = (const float*)d_in[7];
    const float* Wv  = (const float*)d_in[8];
    const float* bv  = (const float*)d_in[9];
    const float* Wp  = (const float*)d_in[10];
    const float* pbu = (const float*)d_in[11];
    const float* pbv = (const float*)d_in[12];
    const float* Wo  = (const float*)d_in[13];
    const float* bo  = (const float*)d_in[14];
    float* out = (float*)d_out;

    const int BT = Bc * Tc;                     // 4096
    // workspace layout (floats): qh | kh | vh | ph | ao   (~36 MB total)
    float* ws = (float*)d_ws;
    float* qh = ws;
    float* kh = qh + (size_t)BT * Dc;
    float* vh = kh + (size_t)BT * Dc;
    float* ph = vh + (size_t)BT * Dc;
    float* ao = ph + (size_t)Pc * Dc;

    dim3 blk(256);
    gemm_awt<<<dim3(Dc / 64, BT / 64), blk, 0, stream>>>(q,  Wq, bq,      qh,  BT, Dc, Dc);
    gemm_awt<<<dim3(Dc / 64, BT / 64), blk, 0, stream>>>(k,  Wk, bk,      kh,  BT, Dc, Dc);
    gemm_awt<<<dim3(Dc / 64, BT / 64), blk, 0, stream>>>(v,  Wv, bv,      vh,  BT, Dc, Dc);
    gemm_awt<<<dim3(Dc / 64, (Pc + 63) / 64), blk, 0, stream>>>(pe, Wp, nullptr, ph, Pc, Dc, Dc);

    relattn<<<dim3(Bc * Hc * (Tc / QB)), blk, 0, stream>>>(qh, kh, vh, ph, pbu, pbv, ao);

    gemm_awt<<<dim3(Dc / 64, BT / 64), blk, 0, stream>>>(ao, Wo, bo, out, BT, Dc, Dc);
}

// Round 2
// 661.616 us; speedup vs baseline: 2.3460x; 2.3460x over previous
//
#include <hip/hip_runtime.h>
#include <math.h>

typedef unsigned short u16;
typedef __attribute__((ext_vector_type(8))) short bf16x8;
typedef __attribute__((ext_vector_type(4))) float f32x4;

#define B_  4
#define T_  1024
#define D_  512
#define H_  8
#define DK_ 64
#define P_  2047

#define MFMA16(a, b, c) __builtin_amdgcn_mfma_f32_16x16x32_bf16(a, b, c, 0, 0, 0)

__device__ __forceinline__ u16 f2bf(float x) {
    union { float f; unsigned u; } c; c.f = x;
    unsigned r = c.u + 0x7FFFu + ((c.u >> 16) & 1u);
    return (u16)(r >> 16);
}
__device__ __forceinline__ void splitbf(float x, u16& h, u16& l) {
    h = f2bf(x);
    union { unsigned u; float f; } hb; hb.u = ((unsigned)h) << 16;
    l = f2bf(x - hb.f);
}

// ---------------------------------------------------------------------------
// fp32 GEMM: C[M,N] = A[M,K] @ W[N,K]^T + bias   (unchanged from round 0)
// ---------------------------------------------------------------------------
__global__ __launch_bounds__(256)
void gemm_awt(const float* __restrict__ A, const float* __restrict__ W,
              const float* __restrict__ bias, float* __restrict__ C,
              int M, int N, int K)
{
    __shared__ float As[64][33];
    __shared__ float Ws[64][33];

    const int bm  = blockIdx.y * 64;
    const int bn  = blockIdx.x * 64;
    const int tid = threadIdx.x;
    const int tx  = tid & 15;
    const int ty  = tid >> 4;

    float acc[4][4] = {};

    for (int k0 = 0; k0 < K; k0 += 32) {
        for (int i = tid; i < 64 * 32; i += 256) {
            int r = i >> 5, c = i & 31;
            int m = bm + r;
            As[r][c] = (m < M) ? A[(size_t)m * K + k0 + c] : 0.f;
        }
        for (int i = tid; i < 64 * 32; i += 256) {
            int r = i >> 5, c = i & 31;
            Ws[r][c] = W[(size_t)(bn + r) * K + k0 + c];
        }
        __syncthreads();
        #pragma unroll
        for (int kk = 0; kk < 32; ++kk) {
            float a[4], bb[4];
            #pragma unroll
            for (int i = 0; i < 4; ++i) a[i] = As[ty * 4 + i][kk];
            #pragma unroll
            for (int j = 0; j < 4; ++j) bb[j] = Ws[tx * 4 + j][kk];
            #pragma unroll
            for (int i = 0; i < 4; ++i)
                #pragma unroll
                for (int j = 0; j < 4; ++j)
                    acc[i][j] += a[i] * bb[j];
        }
        __syncthreads();
    }

    #pragma unroll
    for (int i = 0; i < 4; ++i) {
        int m = bm + ty * 4 + i;
        if (m >= M) continue;
        #pragma unroll
        for (int j = 0; j < 4; ++j) {
            int n = bn + tx * 4 + j;
            float v = acc[i][j];
            if (bias) v += bias[n];
            C[(size_t)m * N + n] = v;
        }
    }
}

// ---------------------------------------------------------------------------
// Convert fp32 (Bn, Tn, Hn, 64) -> split bf16 (Bn, Hn, Tn, 64)  (head-major)
// ---------------------------------------------------------------------------
__global__ __launch_bounds__(256)
void conv_split(const float* __restrict__ src, u16* __restrict__ dhi,
                u16* __restrict__ dlo, int Bn, int Tn, int Hn)
{
    int total = Bn * Tn * Hn * 16;   // float4 chunks
    for (int i = blockIdx.x * 256 + threadIdx.x; i < total; i += gridDim.x * 256) {
        int d4 = i & 15, rest = i >> 4;
        int hh = rest % Hn; rest /= Hn;
        int t  = rest % Tn;
        int bb = rest / Tn;
        float4 v = *(const float4*)(src + (size_t)i * 4);
        size_t o = ((size_t)(bb * Hn + hh) * Tn + t) * 64 + d4 * 4;
        u16 hs[4], ls[4];
        splitbf(v.x, hs[0], ls[0]); splitbf(v.y, hs[1], ls[1]);
        splitbf(v.z, hs[2], ls[2]); splitbf(v.w, hs[3], ls[3]);
        *(uint2*)(dhi + o) = *(uint2*)hs;
        *(uint2*)(dlo + o) = *(uint2*)ls;
    }
}

// ---------------------------------------------------------------------------
// vh fp32 (B, T, H, 64) -> vt split bf16 (B, H, 64, T)   (transposed)
// ---------------------------------------------------------------------------
__global__ __launch_bounds__(256)
void conv_vt(const float* __restrict__ vh, u16* __restrict__ vth,
             u16* __restrict__ vtl)
{
    __shared__ float tile[64][65];
    int bid = blockIdx.x;                       // b*128 + h*16 + tt
    int tt = bid & 15, hh = (bid >> 4) & 7, bb = bid >> 7;
    int t0 = tt * 64;

    for (int i = threadIdx.x; i < 1024; i += 256) {   // 64 rows x 16 float4
        int r = i >> 4, c4 = i & 15;
        float4 v = *(const float4*)(vh + ((size_t)(bb * T_ + t0 + r) * H_ + hh) * 64 + c4 * 4);
        tile[r][c4 * 4 + 0] = v.x; tile[r][c4 * 4 + 1] = v.y;
        tile[r][c4 * 4 + 2] = v.z; tile[r][c4 * 4 + 3] = v.w;
    }
    __syncthreads();

    int d  = threadIdx.x >> 2;
    int kc = (threadIdx.x & 3) * 16;
    u16 hb[16], lb[16];
    #pragma unroll
    for (int i = 0; i < 16; ++i) splitbf(tile[kc + i][d], hb[i], lb[i]);
    size_t o = ((size_t)(bb * H_ + hh) * 64 + d) * T_ + t0 + kc;
    *(uint4*)(vth + o)     = ((uint4*)hb)[0];
    *(uint4*)(vth + o + 8) = ((uint4*)hb)[1];
    *(uint4*)(vtl + o)     = ((uint4*)lb)[0];
    *(uint4*)(vtl + o + 8) = ((uint4*)lb)[1];
}

// ---------------------------------------------------------------------------
// Fused relative-position attention, MFMA (16x16x32 bf16), split-bf16 scores.
// Block = (b, h, 64 q rows), 4 waves, wave w owns q rows [w*16, w*16+16).
// Per K-tile (64 cols): AC = (q+u)K^T, BD = (q+v)Phband^T (128-wide band,
// shift-read via LDS), online softmax, O += P V.
// ---------------------------------------------------------------------------
__device__ __forceinline__ int swz8(int row, int colbase) {   // colbase % 8 == 0
    return row * 64 + (((colbase >> 3) ^ (row & 7)) << 3);
}
__device__ __forceinline__ bf16x8 ldfrag(const u16* base, int row, int colbase) {
    return *(const bf16x8*)(base + swz8(row, colbase));
}

__global__ __launch_bounds__(256, 2)
void relattn_mfma(const float* __restrict__ qh,
                  const u16* __restrict__ khh, const u16* __restrict__ khl,
                  const u16* __restrict__ vth,
                  const u16* __restrict__ phh, const u16* __restrict__ phl,
                  const float* __restrict__ pbu, const float* __restrict__ pbv,
                  float* __restrict__ ao)
{
    __shared__ u16 s_k[2][64][64];      // [plane][k][d]  swizzled
    __shared__ u16 s_p[2][128][64];     // [plane][jj][d] swizzled; aliased by s_bd
    __shared__ u16 s_vt[64][64];        // [d][k]         swizzled
    __shared__ u16 s_pp[64][64];        // [q][k]         swizzled
    float* s_bd = (float*)&s_p[0][0][0];   // [64][128] fp32 overlay (32 KB)
    u16*   s_ppu = &s_pp[0][0];

    const int tid = threadIdx.x;
    const int ln  = tid & 63;
    const int w   = tid >> 6;
    const int arow = ln & 15;       // A/B-frag row-in-tile
    const int kseg = ln >> 4;       // 0..3

    const int bid = blockIdx.x;     // b*128 + h*16 + qt
    const int qt = bid & 15, h = (bid >> 4) & 7, b = bid >> 7;
    const int q0 = qt * 64;

    // ---- Q fragments in registers (scaled by 1/8, +u / +v, split hi/lo) ----
    bf16x8 quh[2], qul[2], qvh[2], qvl[2];
    #pragma unroll
    for (int c = 0; c < 2; ++c) {
        const float* qp = qh + ((size_t)(b * T_ + q0 + w * 16 + arow)) * D_ + h * DK_ + c * 32 + kseg * 8;
        float4 a0 = *(const float4*)qp;
        float4 a1 = *(const float4*)(qp + 4);
        const float* up = pbu + h * DK_ + c * 32 + kseg * 8;
        const float* vp = pbv + h * DK_ + c * 32 + kseg * 8;
        float4 u0 = *(const float4*)up, u1 = *(const float4*)(up + 4);
        float4 v0 = *(const float4*)vp, v1 = *(const float4*)(vp + 4);
        float qa[8] = {a0.x, a0.y, a0.z, a0.w, a1.x, a1.y, a1.z, a1.w};
        float ua[8] = {u0.x, u0.y, u0.z, u0.w, u1.x, u1.y, u1.z, u1.w};
        float va[8] = {v0.x, v0.y, v0.z, v0.w, v1.x, v1.y, v1.z, v1.w};
        #pragma unroll
        for (int i = 0; i < 8; ++i) {
            u16 hh2, ll2;
            splitbf((qa[i] + ua[i]) * 0.125f, hh2, ll2);
            quh[c][i] = (short)hh2; qul[c][i] = (short)ll2;
            splitbf((qa[i] + va[i]) * 0.125f, hh2, ll2);
            qvh[c][i] = (short)hh2; qvl[c][i] = (short)ll2;
        }
    }

    f32x4 o_[4] = {};
    float m_run[4] = {-1e30f, -1e30f, -1e30f, -1e30f};
    float l_run[4] = {};

    const size_t kvbase = (size_t)(b * H_ + h) * T_ * 64;
    const size_t vtbase = (size_t)(b * H_ + h) * 64 * T_;
    const size_t pbase  = (size_t)h * P_ * 64;

    for (int t = 0; t < 16; ++t) {
        const int k0 = t * 64;
        const int jbase = (T_ - 1) + k0 - q0 - 63;

        // ---------------- stage K, P-band, V ----------------
        #pragma unroll
        for (int it = 0; it < 4; ++it) {                 // K: 2 planes x 512 chunks
            int idx = tid + it * 256;
            int pl = idx >> 9, r = (idx >> 3) & 63, ch = idx & 7;
            const u16* src = (pl ? khl : khh) + kvbase + (size_t)(k0 + r) * 64 + ch * 8;
            *(bf16x8*)(&s_k[pl][0][0] + swz8(r, ch * 8)) = *(const bf16x8*)src;
        }
        #pragma unroll
        for (int it = 0; it < 8; ++it) {                 // P: 2 planes x 1024 chunks
            int idx = tid + it * 256;
            int pl = idx >> 10, r = (idx >> 3) & 127, ch = idx & 7;
            int j = jbase + r; if (j > P_ - 1) j = P_ - 1;   // row 127 never read
            const u16* src = (pl ? phl : phh) + pbase + (size_t)j * 64 + ch * 8;
            *(bf16x8*)(&s_p[pl][0][0] + swz8(r, ch * 8)) = *(const bf16x8*)src;
        }
        #pragma unroll
        for (int it = 0; it < 2; ++it) {                 // V: 512 chunks
            int idx = tid + it * 256;
            int r = idx >> 3, ch = idx & 7;
            const u16* src = vth + vtbase + (size_t)r * T_ + k0 + ch * 8;
            *(bf16x8*)(&s_vt[0][0] + swz8(r, ch * 8)) = *(const bf16x8*)src;
        }
        __syncthreads();

        // ---------------- AC + BD MFMA ----------------
        f32x4 ac[4] = {};
        #pragma unroll
        for (int nt = 0; nt < 4; ++nt) {
            int kr = nt * 16 + arow;
            bf16x8 b0h = ldfrag(&s_k[0][0][0], kr, kseg * 8);
            bf16x8 b1h = ldfrag(&s_k[0][0][0], kr, 32 + kseg * 8);
            bf16x8 b0l = ldfrag(&s_k[1][0][0], kr, kseg * 8);
            bf16x8 b1l = ldfrag(&s_k[1][0][0], kr, 32 + kseg * 8);
            ac[nt] = MFMA16(quh[0], b0h, ac[nt]);
            ac[nt] = MFMA16(quh[1], b1h, ac[nt]);
            ac[nt] = MFMA16(quh[0], b0l, ac[nt]);
            ac[nt] = MFMA16(quh[1], b1l, ac[nt]);
            ac[nt] = MFMA16(qul[0], b0h, ac[nt]);
            ac[nt] = MFMA16(qul[1], b1h, ac[nt]);
        }
        f32x4 bd[8] = {};
        #pragma unroll
        for (int nb = 0; nb < 8; ++nb) {
            int pr = nb * 16 + arow;
            bf16x8 b0h = ldfrag(&s_p[0][0][0], pr, kseg * 8);
            bf16x8 b1h = ldfrag(&s_p[0][0][0], pr, 32 + kseg * 8);
            bf16x8 b0l = ldfrag(&s_p[1][0][0], pr, kseg * 8);
            bf16x8 b1l = ldfrag(&s_p[1][0][0], pr, 32 + kseg * 8);
            bd[nb] = MFMA16(qvh[0], b0h, bd[nb]);
            bd[nb] = MFMA16(qvh[1], b1h, bd[nb]);
            bd[nb] = MFMA16(qvh[0], b0l, bd[nb]);
            bd[nb] = MFMA16(qvh[1], b1l, bd[nb]);
            bd[nb] = MFMA16(qvl[0], b0h, bd[nb]);
            bd[nb] = MFMA16(qvl[1], b1h, bd[nb]);
        }
        __syncthreads();   // all BD reads of s_p done before fp32 overlay write

        // ---------------- BD -> LDS (shift staging) ----------------
        #pragma unroll
        for (int nb = 0; nb < 8; ++nb)
            #pragma unroll
            for (int r = 0; r < 4; ++r)
                s_bd[(w * 16 + kseg * 4 + r) * 128 + nb * 16 + arow] = bd[nb][r];
        __syncthreads();

        // ---------------- gather shifted BD + online softmax ----------------
        float sm[4][4];
        #pragma unroll
        for (int nt = 0; nt < 4; ++nt)
            #pragma unroll
            for (int r = 0; r < 4; ++r) {
                int qld = w * 16 + kseg * 4 + r;
                int jj  = nt * 16 + arow + 63 - qld;
                sm[nt][r] = ac[nt][r] + s_bd[qld * 128 + jj];
            }
        #pragma unroll
        for (int r = 0; r < 4; ++r) {
            float mxv = fmaxf(fmaxf(sm[0][r], sm[1][r]), fmaxf(sm[2][r], sm[3][r]));
            #pragma unroll
            for (int off = 8; off; off >>= 1) mxv = fmaxf(mxv, __shfl_xor(mxv, off));
            float mnew = fmaxf(m_run[r], mxv);
            float fac = __expf(m_run[r] - mnew);
            m_run[r] = mnew;
            float ps = 0.f;
            int qld = w * 16 + kseg * 4 + r;
            #pragma unroll
            for (int nt = 0; nt < 4; ++nt) {
                float p = __expf(sm[nt][r] - mnew);
                ps += p;
                int kl = nt * 16 + arow;
                s_ppu[qld * 64 + ((((kl >> 3) ^ (qld & 7)) << 3) | (kl & 7))] = f2bf(p);
            }
            #pragma unroll
            for (int off = 8; off; off >>= 1) ps += __shfl_xor(ps, off);
            l_run[r] = l_run[r] * fac + ps;
            #pragma unroll
            for (int nt = 0; nt < 4; ++nt) o_[nt][r] *= fac;
        }
        __syncthreads();

        // ---------------- PV MFMA ----------------
        bf16x8 pa0 = ldfrag(s_ppu, w * 16 + arow, kseg * 8);
        bf16x8 pa1 = ldfrag(s_ppu, w * 16 + arow, 32 + kseg * 8);
        #pragma unroll
        for (int nt = 0; nt < 4; ++nt) {
            int vr = nt * 16 + arow;
            bf16x8 vb0 = ldfrag(&s_vt[0][0], vr, kseg * 8);
            bf16x8 vb1 = ldfrag(&s_vt[0][0], vr, 32 + kseg * 8);
            o_[nt] = MFMA16(pa0, vb0, o_[nt]);
            o_[nt] = MFMA16(pa1, vb1, o_[nt]);
        }
        __syncthreads();   // before next tile's staging overwrites buffers
    }

    // ---------------- epilogue ----------------
    #pragma unroll
    for (int nt = 0; nt < 4; ++nt)
        #pragma unroll
        for (int r = 0; r < 4; ++r) {
            int qrow = q0 + w * 16 + kseg * 4 + r;
            ao[((size_t)(b * T_ + qrow)) * D_ + h * DK_ + nt * 16 + arow] = o_[nt][r] / l_run[r];
        }
}

// ---------------------------------------------------------------------------
extern "C" void kernel_launch(void* const* d_in, const int* in_sizes, int n_in,
                              void* d_out, int out_size, void* d_ws, size_t ws_size,
                              hipStream_t stream)
{
    const float* q   = (const float*)d_in[0];
    const float* k   = (const float*)d_in[1];
    const float* v   = (const float*)d_in[2];
    const float* pe  = (const float*)d_in[3];
    const float* Wq  = (const float*)d_in[4];
    const float* bq  = (const float*)d_in[5];
    const float* Wk  = (const float*)d_in[6];
    const float* bk  = (const float*)d_in[7];
    const float* Wv  = (const float*)d_in[8];
    const float* bv  = (const float*)d_in[9];
    const float* Wp  = (const float*)d_in[10];
    const float* pbu = (const float*)d_in[11];
    const float* pbv = (const float*)d_in[12];
    const float* Wo  = (const float*)d_in[13];
    const float* bo  = (const float*)d_in[14];
    float* out = (float*)d_out;

    const int BT = B_ * T_;                 // 4096
    char* ws = (char*)d_ws;
    const size_t MB = 1024 * 1024;
    float* qh   = (float*)(ws);             // 8 MB
    float* kh   = (float*)(ws + 8 * MB);    // 8 MB, later reused as ao
    float* vh   = (float*)(ws + 16 * MB);   // 8 MB, later reused by ph2
    float* ph   = (float*)(ws + 24 * MB);   // 4.2 MB
    u16*   kh2h = (u16*)  (ws + 29 * MB);   // 4 MB
    u16*   kh2l = (u16*)  (ws + 33 * MB);   // 4 MB
    u16*   vth  = (u16*)  (ws + 37 * MB);   // 4 MB
    u16*   vtl  = (u16*)  (ws + 41 * MB);   // 4 MB  -> total 45 MB
    u16*   ph2h = (u16*)  (ws + 16 * MB);   // 2.1 MB (over dead vh)
    u16*   ph2l = (u16*)  (ws + 20 * MB);   // 2.1 MB
    float* ao   = kh;                       // over dead kh

    dim3 blk(256);
    gemm_awt<<<dim3(D_ / 64, BT / 64), blk, 0, stream>>>(q,  Wq, bq,      qh, BT, D_, D_);
    gemm_awt<<<dim3(D_ / 64, BT / 64), blk, 0, stream>>>(k,  Wk, bk,      kh, BT, D_, D_);
    gemm_awt<<<dim3(D_ / 64, BT / 64), blk, 0, stream>>>(v,  Wv, bv,      vh, BT, D_, D_);
    gemm_awt<<<dim3(D_ / 64, (P_ + 63) / 64), blk, 0, stream>>>(pe, Wp, nullptr, ph, P_, D_, D_);

    conv_split<<<dim3(2048), blk, 0, stream>>>(kh, kh2h, kh2l, B_, T_, H_);
    conv_vt   <<<dim3(512),  blk, 0, stream>>>(vh, vth, vtl);
    conv_split<<<dim3(1024), blk, 0, stream>>>(ph, ph2h, ph2l, 1, P_, H_);

    relattn_mfma<<<dim3(512), blk, 0, stream>>>(qh, kh2h, kh2l, vth, ph2h, ph2l,
                                                pbu, pbv, ao);

    gemm_awt<<<dim3(D_ / 64, BT / 64), blk, 0, stream>>>(ao, Wo, bo, out, BT, D_, D_);
}

// Round 4
// 213.530 us; speedup vs baseline: 7.2689x; 3.0985x over previous
//
#include <hip/hip_runtime.h>
#include <math.h>

typedef unsigned short u16;
typedef __attribute__((ext_vector_type(8))) short bf16x8;
typedef __attribute__((ext_vector_type(4))) float f32x4;

#define B_  4
#define T_  1024
#define D_  512
#define H_  8
#define DK_ 64
#define P_  2047

#define MFMA16(a, b, c) __builtin_amdgcn_mfma_f32_16x16x32_bf16(a, b, c, 0, 0, 0)

__device__ __forceinline__ u16 f2bf(float x) {
    union { float f; unsigned u; } c; c.f = x;
    unsigned r = c.u + 0x7FFFu + ((c.u >> 16) & 1u);
    return (u16)(r >> 16);
}
__device__ __forceinline__ void splitbf(float x, u16& h, u16& l) {
    h = f2bf(x);
    union { unsigned u; float f; } hb; hb.u = ((unsigned)h) << 16;
    l = f2bf(x - hb.f);
}

__device__ __forceinline__ void gload_lds16(const u16* g, u16* l) {
    __builtin_amdgcn_global_load_lds(
        (const __attribute__((address_space(1))) void*)g,
        (__attribute__((address_space(3))) void*)l, 16, 0, 0);
}

// ---------------------------------------------------------------------------
// One-shot conversion: inputs q,k,v,pe and 5 weights -> split bf16 planes.
// ---------------------------------------------------------------------------
__global__ __launch_bounds__(256)
void conv_all(const float* __restrict__ q, const float* __restrict__ k,
              const float* __restrict__ v, const float* __restrict__ pe,
              const float* __restrict__ wq, const float* __restrict__ wk,
              const float* __restrict__ wv, const float* __restrict__ wp,
              const float* __restrict__ wo,
              u16* qsh, u16* qsl, u16* ksh, u16* ksl, u16* vsh, u16* vsl,
              u16* pesh, u16* pesl,
              u16* wqh, u16* wql, u16* wkh, u16* wkl, u16* wvh, u16* wvl,
              u16* wph, u16* wpl, u16* woh, u16* wol)
{
    const int NQ = 524288;     // float4 chunks in q/k/v (2^21 floats)
    const int NPE = 262016;    // 2047*512/4
    const int NW = 65536;      // 512*512/4
    const int TOT = 3 * NQ + NPE + 5 * NW;
    for (int i = blockIdx.x * 256 + threadIdx.x; i < TOT; i += gridDim.x * 256) {
        const float* src; u16 *dh, *dl; int off;
        int j = i;
        if (j < NQ)              { src = q;  dh = qsh;  dl = qsl;  off = j; }
        else if ((j -= NQ) < NQ) { src = k;  dh = ksh;  dl = ksl;  off = j; }
        else if ((j -= NQ) < NQ) { src = v;  dh = vsh;  dl = vsl;  off = j; }
        else if ((j -= NQ) < NPE){ src = pe; dh = pesh; dl = pesl; off = j; }
        else if ((j -= NPE) < NW){ src = wq; dh = wqh;  dl = wql;  off = j; }
        else if ((j -= NW) < NW) { src = wk; dh = wkh;  dl = wkl;  off = j; }
        else if ((j -= NW) < NW) { src = wv; dh = wvh;  dl = wvl;  off = j; }
        else if ((j -= NW) < NW) { src = wp; dh = wph;  dl = wpl;  off = j; }
        else                     { j -= NW; src = wo; dh = woh; dl = wol; off = j; }
        float4 x = *(const float4*)(src + (size_t)off * 4);
        u16 hs[4], ls[4];
        splitbf(x.x, hs[0], ls[0]); splitbf(x.y, hs[1], ls[1]);
        splitbf(x.z, hs[2], ls[2]); splitbf(x.w, hs[3], ls[3]);
        *(uint2*)(dh + (size_t)off * 4) = *(uint2*)hs;
        *(uint2*)(dl + (size_t)off * 4) = *(uint2*)ls;
    }
}

// ---------------------------------------------------------------------------
// Split-bf16 MFMA GEMM: C[M,512] = A[M,512] @ W[512,512]^T + bias
// 3-term split (AhBh + AhBl + AlBh). BM=128 BN=64 BK=64, 4 waves (2x2).
// global_load_lds staging, source-XOR-swizzled so ds_read_b128 is ~2-way.
// MODE 0: fp32 row-major.  MODE 1: split bf16 head-major (b,h,t,64).
// MODE 2: bf16-hi transposed (b,h,64,t).
// ---------------------------------------------------------------------------
template<int MODE>
__global__ __launch_bounds__(256, 2)
void gemm_mfma(const u16* __restrict__ Ah, const u16* __restrict__ Al,
               const u16* __restrict__ Bh, const u16* __restrict__ Bl,
               const float* __restrict__ bias,
               float* __restrict__ C, u16* __restrict__ Ch, u16* __restrict__ Cl,
               int M, int Tn)
{
    __shared__ u16 sA[2][128][64];
    __shared__ u16 sB[2][64][64];

    const int tid = threadIdx.x;
    const int ln = tid & 63, w = tid >> 6;
    const int arow = ln & 15, kseg = ln >> 4;
    const int wr = w >> 1, wc = w & 1;
    const int bn = blockIdx.x * 64;
    const int bm = blockIdx.y * 128;

    f32x4 acc[4][2] = {};

    for (int k0 = 0; k0 < 512; k0 += 64) {
        #pragma unroll
        for (int pl = 0; pl < 2; ++pl) {
            const u16* As = pl ? Al : Ah;
            #pragma unroll
            for (int it = 0; it < 4; ++it) {
                int ch = it * 256 + tid;            // 0..1023
                int r = ch >> 3, j = ch & 7;
                int rm = bm + r; if (rm > M - 1) rm = M - 1;
                gload_lds16(As + (size_t)rm * 512 + k0 + ((j ^ (r & 7)) << 3),
                            &sA[pl][0][0] + ch * 8);
            }
            const u16* Bs = pl ? Bl : Bh;
            #pragma unroll
            for (int it = 0; it < 2; ++it) {
                int ch = it * 256 + tid;            // 0..511
                int r = ch >> 3, j = ch & 7;
                gload_lds16(Bs + (size_t)(bn + r) * 512 + k0 + ((j ^ (r & 7)) << 3),
                            &sB[pl][0][0] + ch * 8);
            }
        }
        __syncthreads();

        bf16x8 af[2][4][2];
        bf16x8 bf[2][2][2];
        #pragma unroll
        for (int pl = 0; pl < 2; ++pl) {
            #pragma unroll
            for (int mi = 0; mi < 4; ++mi) {
                int row = wr * 64 + mi * 16 + arow;
                #pragma unroll
                for (int kc = 0; kc < 2; ++kc)
                    af[pl][mi][kc] = *(const bf16x8*)
                        (&sA[pl][row][0] + ((((kc << 2) | kseg) ^ (row & 7)) << 3));
            }
            #pragma unroll
            for (int nj = 0; nj < 2; ++nj) {
                int row = wc * 32 + nj * 16 + arow;
                #pragma unroll
                for (int kc = 0; kc < 2; ++kc)
                    bf[pl][nj][kc] = *(const bf16x8*)
                        (&sB[pl][row][0] + ((((kc << 2) | kseg) ^ (row & 7)) << 3));
            }
        }
        #pragma unroll
        for (int mi = 0; mi < 4; ++mi)
            #pragma unroll
            for (int nj = 0; nj < 2; ++nj)
                #pragma unroll
                for (int kc = 0; kc < 2; ++kc) {
                    acc[mi][nj] = MFMA16(af[0][mi][kc], bf[0][nj][kc], acc[mi][nj]);
                    acc[mi][nj] = MFMA16(af[0][mi][kc], bf[1][nj][kc], acc[mi][nj]);
                    acc[mi][nj] = MFMA16(af[1][mi][kc], bf[0][nj][kc], acc[mi][nj]);
                }
        __syncthreads();
    }

    // epilogue
    float bv0[2];
    #pragma unroll
    for (int nj = 0; nj < 2; ++nj)
        bv0[nj] = bias ? bias[bn + wc * 32 + nj * 16 + arow] : 0.f;

    #pragma unroll
    for (int mi = 0; mi < 4; ++mi)
        #pragma unroll
        for (int r = 0; r < 4; ++r) {
            int m = bm + wr * 64 + mi * 16 + kseg * 4 + r;
            if (m >= M) continue;
            #pragma unroll
            for (int nj = 0; nj < 2; ++nj) {
                int n = bn + wc * 32 + nj * 16 + arow;
                float val = acc[mi][nj][r] + bv0[nj];
                if (MODE == 0) {
                    C[(size_t)m * 512 + n] = val;
                } else if (MODE == 1) {
                    int bb = m / Tn, t = m - bb * Tn;
                    int h = n >> 6, d = n & 63;
                    size_t off = ((size_t)(bb * H_ + h) * Tn + t) * 64 + d;
                    u16 hh, ll; splitbf(val, hh, ll);
                    Ch[off] = hh; Cl[off] = ll;
                } else {
                    int bb = m >> 10, t = m & 1023;
                    int h = n >> 6, d = n & 63;
                    size_t off = ((size_t)(bb * H_ + h) * 64 + d) * T_ + t;
                    Ch[off] = f2bf(val);
                }
            }
        }
}

// ---------------------------------------------------------------------------
// Fused relative-position attention (validated core);
// epilogue writes ao as split-bf16 planes.
// ---------------------------------------------------------------------------
__device__ __forceinline__ int swz8(int row, int colbase) {
    return row * 64 + (((colbase >> 3) ^ (row & 7)) << 3);
}
__device__ __forceinline__ bf16x8 ldfrag(const u16* base, int row, int colbase) {
    return *(const bf16x8*)(base + swz8(row, colbase));
}

__global__ __launch_bounds__(256, 2)
void relattn_mfma(const float* __restrict__ qh,
                  const u16* __restrict__ khh, const u16* __restrict__ khl,
                  const u16* __restrict__ vth,
                  const u16* __restrict__ phh, const u16* __restrict__ phl,
                  const float* __restrict__ pbu, const float* __restrict__ pbv,
                  u16* __restrict__ aoh, u16* __restrict__ aol)
{
    __shared__ u16 s_k[2][64][64];
    __shared__ u16 s_p[2][128][64];
    __shared__ u16 s_vt[64][64];
    __shared__ u16 s_pp[64][64];
    float* s_bd = (float*)&s_p[0][0][0];
    u16*   s_ppu = &s_pp[0][0];

    const int tid = threadIdx.x;
    const int ln  = tid & 63;
    const int w   = tid >> 6;
    const int arow = ln & 15;
    const int kseg = ln >> 4;

    const int bid = blockIdx.x;
    const int qt = bid & 15, h = (bid >> 4) & 7, b = bid >> 7;
    const int q0 = qt * 64;

    bf16x8 quh[2], qul[2], qvh[2], qvl[2];
    #pragma unroll
    for (int c = 0; c < 2; ++c) {
        const float* qp = qh + ((size_t)(b * T_ + q0 + w * 16 + arow)) * D_ + h * DK_ + c * 32 + kseg * 8;
        float4 a0 = *(const float4*)qp;
        float4 a1 = *(const float4*)(qp + 4);
        const float* up = pbu + h * DK_ + c * 32 + kseg * 8;
        const float* vp = pbv + h * DK_ + c * 32 + kseg * 8;
        float4 u0 = *(const float4*)up, u1 = *(const float4*)(up + 4);
        float4 v0 = *(const float4*)vp, v1 = *(const float4*)(vp + 4);
        float qa[8] = {a0.x, a0.y, a0.z, a0.w, a1.x, a1.y, a1.z, a1.w};
        float ua[8] = {u0.x, u0.y, u0.z, u0.w, u1.x, u1.y, u1.z, u1.w};
        float va[8] = {v0.x, v0.y, v0.z, v0.w, v1.x, v1.y, v1.z, v1.w};
        #pragma unroll
        for (int i = 0; i < 8; ++i) {
            u16 hh2, ll2;
            splitbf((qa[i] + ua[i]) * 0.125f, hh2, ll2);
            quh[c][i] = (short)hh2; qul[c][i] = (short)ll2;
            splitbf((qa[i] + va[i]) * 0.125f, hh2, ll2);
            qvh[c][i] = (short)hh2; qvl[c][i] = (short)ll2;
        }
    }

    f32x4 o_[4] = {};
    float m_run[4] = {-1e30f, -1e30f, -1e30f, -1e30f};
    float l_run[4] = {};

    const size_t kvbase = (size_t)(b * H_ + h) * T_ * 64;
    const size_t vtbase = (size_t)(b * H_ + h) * 64 * T_;
    const size_t pbase  = (size_t)h * P_ * 64;

    for (int t = 0; t < 16; ++t) {
        const int k0 = t * 64;
        const int jbase = (T_ - 1) + k0 - q0 - 63;

        #pragma unroll
        for (int it = 0; it < 4; ++it) {
            int idx = tid + it * 256;
            int pl = idx >> 9, r = (idx >> 3) & 63, ch = idx & 7;
            const u16* src = (pl ? khl : khh) + kvbase + (size_t)(k0 + r) * 64 + ch * 8;
            *(bf16x8*)(&s_k[pl][0][0] + swz8(r, ch * 8)) = *(const bf16x8*)src;
        }
        #pragma unroll
        for (int it = 0; it < 8; ++it) {
            int idx = tid + it * 256;
            int pl = idx >> 10, r = (idx >> 3) & 127, ch = idx & 7;
            int j = jbase + r; if (j > P_ - 1) j = P_ - 1;
            const u16* src = (pl ? phl : phh) + pbase + (size_t)j * 64 + ch * 8;
            *(bf16x8*)(&s_p[pl][0][0] + swz8(r, ch * 8)) = *(const bf16x8*)src;
        }
        #pragma unroll
        for (int it = 0; it < 2; ++it) {
            int idx = tid + it * 256;
            int r = idx >> 3, ch = idx & 7;
            const u16* src = vth + vtbase + (size_t)r * T_ + k0 + ch * 8;
            *(bf16x8*)(&s_vt[0][0] + swz8(r, ch * 8)) = *(const bf16x8*)src;
        }
        __syncthreads();

        f32x4 ac[4] = {};
        #pragma unroll
        for (int nt = 0; nt < 4; ++nt) {
            int kr = nt * 16 + arow;
            bf16x8 b0h = ldfrag(&s_k[0][0][0], kr, kseg * 8);
            bf16x8 b1h = ldfrag(&s_k[0][0][0], kr, 32 + kseg * 8);
            bf16x8 b0l = ldfrag(&s_k[1][0][0], kr, kseg * 8);
            bf16x8 b1l = ldfrag(&s_k[1][0][0], kr, 32 + kseg * 8);
            ac[nt] = MFMA16(quh[0], b0h, ac[nt]);
            ac[nt] = MFMA16(quh[1], b1h, ac[nt]);
            ac[nt] = MFMA16(quh[0], b0l, ac[nt]);
            ac[nt] = MFMA16(quh[1], b1l, ac[nt]);
            ac[nt] = MFMA16(qul[0], b0h, ac[nt]);
            ac[nt] = MFMA16(qul[1], b1h, ac[nt]);
        }
        f32x4 bd[8] = {};
        #pragma unroll
        for (int nb = 0; nb < 8; ++nb) {
            int pr = nb * 16 + arow;
            bf16x8 b0h = ldfrag(&s_p[0][0][0], pr, kseg * 8);
            bf16x8 b1h = ldfrag(&s_p[0][0][0], pr, 32 + kseg * 8);
            bf16x8 b0l = ldfrag(&s_p[1][0][0], pr, kseg * 8);
            bf16x8 b1l = ldfrag(&s_p[1][0][0], pr, 32 + kseg * 8);
            bd[nb] = MFMA16(qvh[0], b0h, bd[nb]);
            bd[nb] = MFMA16(qvh[1], b1h, bd[nb]);
            bd[nb] = MFMA16(qvh[0], b0l, bd[nb]);
            bd[nb] = MFMA16(qvh[1], b1l, bd[nb]);
            bd[nb] = MFMA16(qvl[0], b0h, bd[nb]);
            bd[nb] = MFMA16(qvl[1], b1h, bd[nb]);
        }
        __syncthreads();

        #pragma unroll
        for (int nb = 0; nb < 8; ++nb)
            #pragma unroll
            for (int r = 0; r < 4; ++r)
                s_bd[(w * 16 + kseg * 4 + r) * 128 + nb * 16 + arow] = bd[nb][r];
        __syncthreads();

        float sm[4][4];
        #pragma unroll
        for (int nt = 0; nt < 4; ++nt)
            #pragma unroll
            for (int r = 0; r < 4; ++r) {
                int qld = w * 16 + kseg * 4 + r;
                int jj  = nt * 16 + arow + 63 - qld;
                sm[nt][r] = ac[nt][r] + s_bd[qld * 128 + jj];
            }
        #pragma unroll
        for (int r = 0; r < 4; ++r) {
            float mxv = fmaxf(fmaxf(sm[0][r], sm[1][r]), fmaxf(sm[2][r], sm[3][r]));
            #pragma unroll
            for (int off = 8; off; off >>= 1) mxv = fmaxf(mxv, __shfl_xor(mxv, off));
            float mnew = fmaxf(m_run[r], mxv);
            float fac = __expf(m_run[r] - mnew);
            m_run[r] = mnew;
            float ps = 0.f;
            int qld = w * 16 + kseg * 4 + r;
            #pragma unroll
            for (int nt = 0; nt < 4; ++nt) {
                float p = __expf(sm[nt][r] - mnew);
                ps += p;
                int kl = nt * 16 + arow;
                s_ppu[qld * 64 + ((((kl >> 3) ^ (qld & 7)) << 3) | (kl & 7))] = f2bf(p);
            }
            #pragma unroll
            for (int off = 8; off; off >>= 1) ps += __shfl_xor(ps, off);
            l_run[r] = l_run[r] * fac + ps;
            #pragma unroll
            for (int nt = 0; nt < 4; ++nt) o_[nt][r] *= fac;
        }
        __syncthreads();

        bf16x8 pa0 = ldfrag(s_ppu, w * 16 + arow, kseg * 8);
        bf16x8 pa1 = ldfrag(s_ppu, w * 16 + arow, 32 + kseg * 8);
        #pragma unroll
        for (int nt = 0; nt < 4; ++nt) {
            int vr = nt * 16 + arow;
            bf16x8 vb0 = ldfrag(&s_vt[0][0], vr, kseg * 8);
            bf16x8 vb1 = ldfrag(&s_vt[0][0], vr, 32 + kseg * 8);
            o_[nt] = MFMA16(pa0, vb0, o_[nt]);
            o_[nt] = MFMA16(pa1, vb1, o_[nt]);
        }
        __syncthreads();
    }

    #pragma unroll
    for (int nt = 0; nt < 4; ++nt)
        #pragma unroll
        for (int r = 0; r < 4; ++r) {
            int qrow = q0 + w * 16 + kseg * 4 + r;
            float val = o_[nt][r] / l_run[r];
            u16 hh, ll; splitbf(val, hh, ll);
            size_t off = ((size_t)(b * T_ + qrow)) * D_ + h * DK_ + nt * 16 + arow;
            aoh[off] = hh; aol[off] = ll;
        }
}

// ---------------------------------------------------------------------------
extern "C" void kernel_launch(void* const* d_in, const int* in_sizes, int n_in,
                              void* d_out, int out_size, void* d_ws, size_t ws_size,
                              hipStream_t stream)
{
    const float* q   = (const float*)d_in[0];
    const float* k   = (const float*)d_in[1];
    const float* v   = (const float*)d_in[2];
    const float* pe  = (const float*)d_in[3];
    const float* Wq  = (const float*)d_in[4];
    const float* bq  = (const float*)d_in[5];
    const float* Wk  = (const float*)d_in[6];
    const float* bk  = (const float*)d_in[7];
    const float* Wv  = (const float*)d_in[8];
    const float* bv  = (const float*)d_in[9];
    const float* Wp  = (const float*)d_in[10];
    const float* pbu = (const float*)d_in[11];
    const float* pbv = (const float*)d_in[12];
    const float* Wo  = (const float*)d_in[13];
    const float* bo  = (const float*)d_in[14];
    float* out = (float*)d_out;

    char* ws = (char*)d_ws;
    const size_t MB = 1024 * 1024;
    // region A (0-8MB): q split; later kh split (head-major)
    u16* qsh = (u16*)(ws);            u16* qsl = (u16*)(ws + 4 * MB);
    u16* khh = (u16*)(ws);            u16* khl = (u16*)(ws + 4 * MB);
    // region B (8-16MB): k split; later vt (4MB) + ph split (2+2MB)
    u16* ksh = (u16*)(ws + 8 * MB);   u16* ksl = (u16*)(ws + 12 * MB);
    u16* vth = (u16*)(ws + 8 * MB);
    u16* phh = (u16*)(ws + 12 * MB);  u16* phl = (u16*)(ws + 14 * MB);
    // region C (16-24MB): v split; later ao split
    u16* vsh = (u16*)(ws + 16 * MB);  u16* vsl = (u16*)(ws + 20 * MB);
    u16* aoh = (u16*)(ws + 16 * MB);  u16* aol = (u16*)(ws + 20 * MB);
    // region D (24-28MB): pe split
    u16* pesh = (u16*)(ws + 24 * MB); u16* pesl = (u16*)(ws + 26 * MB);
    // region E (28-33MB): weights split (0.5MB each plane)
    u16* wqh = (u16*)(ws + 28 * MB);          u16* wql = (u16*)(ws + 28 * MB + 512 * 1024);
    u16* wkh = (u16*)(ws + 29 * MB);          u16* wkl = (u16*)(ws + 29 * MB + 512 * 1024);
    u16* wvh = (u16*)(ws + 30 * MB);          u16* wvl = (u16*)(ws + 30 * MB + 512 * 1024);
    u16* wph = (u16*)(ws + 31 * MB);          u16* wpl = (u16*)(ws + 31 * MB + 512 * 1024);
    u16* woh = (u16*)(ws + 32 * MB);          u16* wol = (u16*)(ws + 32 * MB + 512 * 1024);
    // region F (33-41MB): qh fp32
    float* qh = (float*)(ws + 33 * MB);

    dim3 blk(256);
    conv_all<<<dim3(2048), blk, 0, stream>>>(q, k, v, pe, Wq, Wk, Wv, Wp, Wo,
        qsh, qsl, ksh, ksl, vsh, vsl, pesh, pesl,
        wqh, wql, wkh, wkl, wvh, wvl, wph, wpl, woh, wol);

    // q-proj -> fp32 row-major qh
    gemm_mfma<0><<<dim3(8, 32), blk, 0, stream>>>(qsh, qsl, wqh, wql, bq,
                                                  qh, nullptr, nullptr, 4096, T_);
    // k-proj -> split head-major kh
    gemm_mfma<1><<<dim3(8, 32), blk, 0, stream>>>(ksh, ksl, wkh, wkl, bk,
                                                  nullptr, khh, khl, 4096, T_);
    // v-proj -> bf16-hi transposed vt
    gemm_mfma<2><<<dim3(8, 32), blk, 0, stream>>>(vsh, vsl, wvh, wvl, bv,
                                                  nullptr, vth, nullptr, 4096, T_);
    // pos-proj -> split head-major ph  (M=2047, no bias)
    gemm_mfma<1><<<dim3(8, 16), blk, 0, stream>>>(pesh, pesl, wph, wpl, nullptr,
                                                  nullptr, phh, phl, 2047, P_);

    relattn_mfma<<<dim3(512), blk, 0, stream>>>(qh, khh, khl, vth, phh, phl,
                                                pbu, pbv, aoh, aol);

    // out-proj -> fp32 d_out
    gemm_mfma<0><<<dim3(8, 32), blk, 0, stream>>>(aoh, aol, woh, wol, bo,
                                                  out, nullptr, nullptr, 4096, T_);
}

// Round 5
// 153.504 us; speedup vs baseline: 10.1113x; 1.3910x over previous
//
#include <hip/hip_runtime.h>
#include <math.h>

typedef unsigned short u16;
typedef __attribute__((ext_vector_type(8))) short bf16x8;
typedef __attribute__((ext_vector_type(4))) float f32x4;

#define B_  4
#define T_  1024
#define D_  512
#define H_  8
#define DK_ 64
#define P_  2047

#define MFMA16(a, b, c) __builtin_amdgcn_mfma_f32_16x16x32_bf16(a, b, c, 0, 0, 0)

__device__ __forceinline__ u16 f2bf(float x) {
    union { float f; unsigned u; } c; c.f = x;
    unsigned r = c.u + 0x7FFFu + ((c.u >> 16) & 1u);
    return (u16)(r >> 16);
}
__device__ __forceinline__ void splitbf(float x, u16& h, u16& l) {
    h = f2bf(x);
    union { unsigned u; float f; } hb; hb.u = ((unsigned)h) << 16;
    l = f2bf(x - hb.f);
}

__device__ __forceinline__ void gload_lds16(const u16* g, u16* l) {
    __builtin_amdgcn_global_load_lds(
        (const __attribute__((address_space(1))) void*)g,
        (__attribute__((address_space(3))) void*)l, 16, 0, 0);
}

__device__ __forceinline__ int swz8(int row, int colbase) {   // colbase % 8 == 0
    return row * 64 + (((colbase >> 3) ^ (row & 7)) << 3);
}

// ---------------------------------------------------------------------------
// One-shot conversion: inputs q,k,v,pe and 5 weights -> split bf16 planes.
// ---------------------------------------------------------------------------
__global__ __launch_bounds__(256)
void conv_all(const float* __restrict__ q, const float* __restrict__ k,
              const float* __restrict__ v, const float* __restrict__ pe,
              const float* __restrict__ wq, const float* __restrict__ wk,
              const float* __restrict__ wv, const float* __restrict__ wp,
              const float* __restrict__ wo,
              u16* qsh, u16* qsl, u16* ksh, u16* ksl, u16* vsh, u16* vsl,
              u16* pesh, u16* pesl,
              u16* wqh, u16* wql, u16* wkh, u16* wkl, u16* wvh, u16* wvl,
              u16* wph, u16* wpl, u16* woh, u16* wol)
{
    const int NQ = 524288;     // float4 chunks in q/k/v
    const int NPE = 262016;    // 2047*512/4
    const int NW = 65536;      // 512*512/4
    const int TOT = 3 * NQ + NPE + 5 * NW;
    for (int i = blockIdx.x * 256 + threadIdx.x; i < TOT; i += gridDim.x * 256) {
        const float* src; u16 *dh, *dl; int off;
        int j = i;
        if (j < NQ)              { src = q;  dh = qsh;  dl = qsl;  off = j; }
        else if ((j -= NQ) < NQ) { src = k;  dh = ksh;  dl = ksl;  off = j; }
        else if ((j -= NQ) < NQ) { src = v;  dh = vsh;  dl = vsl;  off = j; }
        else if ((j -= NQ) < NPE){ src = pe; dh = pesh; dl = pesl; off = j; }
        else if ((j -= NPE) < NW){ src = wq; dh = wqh;  dl = wql;  off = j; }
        else if ((j -= NW) < NW) { src = wk; dh = wkh;  dl = wkl;  off = j; }
        else if ((j -= NW) < NW) { src = wv; dh = wvh;  dl = wvl;  off = j; }
        else if ((j -= NW) < NW) { src = wp; dh = wph;  dl = wpl;  off = j; }
        else                     { j -= NW; src = wo; dh = woh; dl = wol; off = j; }
        float4 x = *(const float4*)(src + (size_t)off * 4);
        u16 hs[4], ls[4];
        splitbf(x.x, hs[0], ls[0]); splitbf(x.y, hs[1], ls[1]);
        splitbf(x.z, hs[2], ls[2]); splitbf(x.w, hs[3], ls[3]);
        *(uint2*)(dh + (size_t)off * 4) = *(uint2*)hs;
        *(uint2*)(dl + (size_t)off * 4) = *(uint2*)ls;
    }
}

// ---------------------------------------------------------------------------
// Shared GEMM core (identical math to validated round-2 kernel).
// C = A[M,512] @ W[512,512]^T, split-bf16 3-term, BM=128 BN=64 BK=64.
// ---------------------------------------------------------------------------
__device__ __forceinline__ void gemm_core(
    const u16* __restrict__ Ah, const u16* __restrict__ Al,
    const u16* __restrict__ Bh, const u16* __restrict__ Bl,
    int bm, int bn, int M, f32x4 (&acc)[4][2],
    u16 (&sA)[2][128][64], u16 (&sB)[2][64][64])
{
    const int tid = threadIdx.x;
    const int ln = tid & 63, w = tid >> 6;
    const int arow = ln & 15, kseg = ln >> 4;
    const int wr = w >> 1, wc = w & 1;

    for (int k0 = 0; k0 < 512; k0 += 64) {
        #pragma unroll
        for (int pl = 0; pl < 2; ++pl) {
            const u16* As = pl ? Al : Ah;
            #pragma unroll
            for (int it = 0; it < 4; ++it) {
                int ch = it * 256 + tid;
                int r = ch >> 3, j = ch & 7;
                int rm = bm + r; if (rm > M - 1) rm = M - 1;
                gload_lds16(As + (size_t)rm * 512 + k0 + ((j ^ (r & 7)) << 3),
                            &sA[pl][0][0] + ch * 8);
            }
            const u16* Bs = pl ? Bl : Bh;
            #pragma unroll
            for (int it = 0; it < 2; ++it) {
                int ch = it * 256 + tid;
                int r = ch >> 3, j = ch & 7;
                gload_lds16(Bs + (size_t)(bn + r) * 512 + k0 + ((j ^ (r & 7)) << 3),
                            &sB[pl][0][0] + ch * 8);
            }
        }
        __syncthreads();

        bf16x8 af[2][4][2];
        bf16x8 bf[2][2][2];
        #pragma unroll
        for (int pl = 0; pl < 2; ++pl) {
            #pragma unroll
            for (int mi = 0; mi < 4; ++mi) {
                int row = wr * 64 + mi * 16 + arow;
                #pragma unroll
                for (int kc = 0; kc < 2; ++kc)
                    af[pl][mi][kc] = *(const bf16x8*)
                        (&sA[pl][row][0] + ((((kc << 2) | kseg) ^ (row & 7)) << 3));
            }
            #pragma unroll
            for (int nj = 0; nj < 2; ++nj) {
                int row = wc * 32 + nj * 16 + arow;
                #pragma unroll
                for (int kc = 0; kc < 2; ++kc)
                    bf[pl][nj][kc] = *(const bf16x8*)
                        (&sB[pl][row][0] + ((((kc << 2) | kseg) ^ (row & 7)) << 3));
            }
        }
        #pragma unroll
        for (int mi = 0; mi < 4; ++mi)
            #pragma unroll
            for (int nj = 0; nj < 2; ++nj)
                #pragma unroll
                for (int kc = 0; kc < 2; ++kc) {
                    acc[mi][nj] = MFMA16(af[0][mi][kc], bf[0][nj][kc], acc[mi][nj]);
                    acc[mi][nj] = MFMA16(af[0][mi][kc], bf[1][nj][kc], acc[mi][nj]);
                    acc[mi][nj] = MFMA16(af[1][mi][kc], bf[0][nj][kc], acc[mi][nj]);
                }
        __syncthreads();
    }
}

// ---------------------------------------------------------------------------
// Merged projection GEMM: q/k/v/pe in one launch. grid = (8, 112).
//   by  0..31: q-proj -> fp32 qh       by 32..63: k-proj -> split head-major
//   by 64..95: v-proj -> bf16 vt       by 96..111: pe-proj -> split head-major
// ---------------------------------------------------------------------------
__global__ __launch_bounds__(256, 2)
void gemm_qkvp(const u16* __restrict__ qsh, const u16* __restrict__ qsl,
               const u16* __restrict__ ksh, const u16* __restrict__ ksl,
               const u16* __restrict__ vsh, const u16* __restrict__ vsl,
               const u16* __restrict__ pesh, const u16* __restrict__ pesl,
               const u16* __restrict__ wqh, const u16* __restrict__ wql,
               const u16* __restrict__ wkh, const u16* __restrict__ wkl,
               const u16* __restrict__ wvh, const u16* __restrict__ wvl,
               const u16* __restrict__ wph, const u16* __restrict__ wpl,
               const float* __restrict__ bq, const float* __restrict__ bk,
               const float* __restrict__ bv,
               float* __restrict__ qh, u16* __restrict__ khh, u16* __restrict__ khl,
               u16* __restrict__ vth, u16* __restrict__ phh, u16* __restrict__ phl)
{
    __shared__ u16 sA[2][128][64];
    __shared__ u16 sB[2][64][64];

    const int by = blockIdx.y;
    const u16 *Ah, *Al, *Bh, *Bl; const float* bias;
    int seg, bm, M, Tn;
    if (by < 32)      { seg=0; bm=by*128;       Ah=qsh;  Al=qsl;  Bh=wqh; Bl=wql; bias=bq;      M=4096; Tn=T_; }
    else if (by < 64) { seg=1; bm=(by-32)*128;  Ah=ksh;  Al=ksl;  Bh=wkh; Bl=wkl; bias=bk;      M=4096; Tn=T_; }
    else if (by < 96) { seg=2; bm=(by-64)*128;  Ah=vsh;  Al=vsl;  Bh=wvh; Bl=wvl; bias=bv;      M=4096; Tn=T_; }
    else              { seg=3; bm=(by-96)*128;  Ah=pesh; Al=pesl; Bh=wph; Bl=wpl; bias=nullptr; M=P_;   Tn=P_; }
    const int bn = blockIdx.x * 64;

    f32x4 acc[4][2] = {};
    gemm_core(Ah, Al, Bh, Bl, bm, bn, M, acc, sA, sB);

    const int tid = threadIdx.x;
    const int ln = tid & 63, w = tid >> 6;
    const int arow = ln & 15, kseg = ln >> 4;
    const int wr = w >> 1, wc = w & 1;

    float bv0[2];
    #pragma unroll
    for (int nj = 0; nj < 2; ++nj)
        bv0[nj] = bias ? bias[bn + wc * 32 + nj * 16 + arow] : 0.f;

    #pragma unroll
    for (int mi = 0; mi < 4; ++mi)
        #pragma unroll
        for (int r = 0; r < 4; ++r) {
            int m = bm + wr * 64 + mi * 16 + kseg * 4 + r;
            if (m >= M) continue;
            #pragma unroll
            for (int nj = 0; nj < 2; ++nj) {
                int n = bn + wc * 32 + nj * 16 + arow;
                float val = acc[mi][nj][r] + bv0[nj];
                if (seg == 0) {
                    qh[(size_t)m * 512 + n] = val;
                } else if (seg == 2) {
                    int bb = m >> 10, t = m & 1023;
                    int hh = n >> 6, d = n & 63;
                    vth[((size_t)(bb * H_ + hh) * 64 + d) * T_ + t] = f2bf(val);
                } else {
                    int bb = (Tn == T_) ? (m >> 10) : 0;
                    int t = m - bb * Tn;
                    int hh = n >> 6, d = n & 63;
                    size_t off = ((size_t)(bb * H_ + hh) * Tn + t) * 64 + d;
                    u16 h2, l2; splitbf(val, h2, l2);
                    if (seg == 1) { khh[off] = h2; khl[off] = l2; }
                    else          { phh[off] = h2; phl[off] = l2; }
                }
            }
        }
}

// ---------------------------------------------------------------------------
// Output projection (fp32 out)
// ---------------------------------------------------------------------------
__global__ __launch_bounds__(256, 2)
void gemm_out(const u16* __restrict__ Ah, const u16* __restrict__ Al,
              const u16* __restrict__ Bh, const u16* __restrict__ Bl,
              const float* __restrict__ bias, float* __restrict__ C)
{
    __shared__ u16 sA[2][128][64];
    __shared__ u16 sB[2][64][64];
    const int bn = blockIdx.x * 64;
    const int bm = blockIdx.y * 128;
    f32x4 acc[4][2] = {};
    gemm_core(Ah, Al, Bh, Bl, bm, bn, 4096, acc, sA, sB);

    const int tid = threadIdx.x;
    const int ln = tid & 63, w = tid >> 6;
    const int arow = ln & 15, kseg = ln >> 4;
    const int wr = w >> 1, wc = w & 1;
    #pragma unroll
    for (int mi = 0; mi < 4; ++mi)
        #pragma unroll
        for (int r = 0; r < 4; ++r) {
            int m = bm + wr * 64 + mi * 16 + kseg * 4 + r;
            #pragma unroll
            for (int nj = 0; nj < 2; ++nj) {
                int n = bn + wc * 32 + nj * 16 + arow;
                C[(size_t)m * 512 + n] = acc[mi][nj][r] + bias[n];
            }
        }
}

// ---------------------------------------------------------------------------
// Fused relative-position attention, pipelined 1-barrier/iter version.
// Block = (b,h,64 q rows), 4 waves. K double-buffered, P 64-row ring with
// register BD-carry, V direct-from-global, s_bd 16KB two-round shift buffer
// (s_pp overlaid per-wave). XCD-swizzled blockIdx.
// ---------------------------------------------------------------------------
__global__ __launch_bounds__(256, 2)
void relattn_mfma(const float* __restrict__ qh,
                  const u16* __restrict__ khh, const u16* __restrict__ khl,
                  const u16* __restrict__ vth,
                  const u16* __restrict__ phh, const u16* __restrict__ phl,
                  const float* __restrict__ pbu, const float* __restrict__ pbv,
                  u16* __restrict__ aoh, u16* __restrict__ aol)
{
    __shared__ u16 s_k[2][2][64][64];   // [buf][plane][k][d]   32 KB
    __shared__ u16 s_p[2][2][64][64];   // [slot][plane][j][d]  32 KB (ring)
    __shared__ float s_bd[64][64];      // 16 KB shift buffer; s_pp overlay

    const int tid = threadIdx.x;
    const int ln  = tid & 63;
    const int w   = tid >> 6;
    const int arow = ln & 15;
    const int kseg = ln >> 4;

    // XCD swizzle: 512 blocks, 8 XCDs -> each XCD gets 4 whole (b,h) groups
    const int lg = ((blockIdx.x & 7) << 6) | (blockIdx.x >> 3);
    const int qt = lg & 15, h = (lg >> 4) & 7, b = lg >> 7;
    const int q0 = qt * 64;

    // ---- Q fragments (scaled 1/8, +u/+v, split hi/lo) ----
    bf16x8 quh[2], qul[2], qvh[2], qvl[2];
    #pragma unroll
    for (int c = 0; c < 2; ++c) {
        const float* qp = qh + ((size_t)(b * T_ + q0 + w * 16 + arow)) * D_ + h * DK_ + c * 32 + kseg * 8;
        float4 a0 = *(const float4*)qp;
        float4 a1 = *(const float4*)(qp + 4);
        const float* up = pbu + h * DK_ + c * 32 + kseg * 8;
        const float* vp = pbv + h * DK_ + c * 32 + kseg * 8;
        float4 u0 = *(const float4*)up, u1 = *(const float4*)(up + 4);
        float4 v0 = *(const float4*)vp, v1 = *(const float4*)(vp + 4);
        float qa[8] = {a0.x, a0.y, a0.z, a0.w, a1.x, a1.y, a1.z, a1.w};
        float ua[8] = {u0.x, u0.y, u0.z, u0.w, u1.x, u1.y, u1.z, u1.w};
        float va[8] = {v0.x, v0.y, v0.z, v0.w, v1.x, v1.y, v1.z, v1.w};
        #pragma unroll
        for (int i = 0; i < 8; ++i) {
            u16 hh2, ll2;
            splitbf((qa[i] + ua[i]) * 0.125f, hh2, ll2);
            quh[c][i] = (short)hh2; qul[c][i] = (short)ll2;
            splitbf((qa[i] + va[i]) * 0.125f, hh2, ll2);
            qvh[c][i] = (short)hh2; qvl[c][i] = (short)ll2;
        }
    }

    f32x4 o_[4] = {};
    float m_run[4] = {-1e30f, -1e30f, -1e30f, -1e30f};
    float l_run[4] = {};

    const size_t kvbase = (size_t)(b * H_ + h) * T_ * 64;
    const size_t vtbase = (size_t)(b * H_ + h) * 64 * T_;
    const size_t pbase  = (size_t)h * P_ * 64;
    const int jb0 = 960 - q0;                 // j of chunk 0 row 0 (>= 0)

    u16* ppw = (u16*)&s_bd[w * 16][0];        // this wave's 4 KB region

    auto stage_k = [&](int kt, int buf) {
        #pragma unroll
        for (int it = 0; it < 4; ++it) {
            int idx = tid + it * 256;
            int pl = idx >> 9, r = (idx >> 3) & 63, ch = idx & 7;
            const u16* src = (pl ? khl : khh) + kvbase + (size_t)(kt * 64 + r) * 64 + ((ch ^ (r & 7)) << 3);
            gload_lds16(src, &s_k[buf][0][0][0] + idx * 8);
        }
    };
    auto stage_p = [&](int c, int slot) {
        #pragma unroll
        for (int it = 0; it < 4; ++it) {
            int idx = tid + it * 256;
            int pl = idx >> 9, r = (idx >> 3) & 63, ch = idx & 7;
            int j = jb0 + c * 64 + r; if (j > P_ - 1) j = P_ - 1;
            const u16* src = (pl ? phl : phh) + pbase + (size_t)j * 64 + ((ch ^ (r & 7)) << 3);
            gload_lds16(src, &s_p[slot][0][0][0] + idx * 8);
        }
    };
    auto bd_chunk = [&](int slot, f32x4* out) {
        #pragma unroll
        for (int nb = 0; nb < 4; ++nb) {
            int pr = nb * 16 + arow;
            bf16x8 b0h = *(const bf16x8*)(&s_p[slot][0][0][0] + swz8(pr, kseg * 8));
            bf16x8 b1h = *(const bf16x8*)(&s_p[slot][0][0][0] + swz8(pr, 32 + kseg * 8));
            bf16x8 b0l = *(const bf16x8*)(&s_p[slot][1][0][0] + swz8(pr, kseg * 8));
            bf16x8 b1l = *(const bf16x8*)(&s_p[slot][1][0][0] + swz8(pr, 32 + kseg * 8));
            out[nb] = MFMA16(qvh[0], b0h, out[nb]);
            out[nb] = MFMA16(qvh[1], b1h, out[nb]);
            out[nb] = MFMA16(qvh[0], b0l, out[nb]);
            out[nb] = MFMA16(qvh[1], b1l, out[nb]);
            out[nb] = MFMA16(qvl[0], b0h, out[nb]);
            out[nb] = MFMA16(qvl[1], b1h, out[nb]);
        }
    };

    // ---- prologue: K0, P-chunks 0,1; BD on chunk 0 -> carry ----
    stage_k(0, 0); stage_p(0, 0); stage_p(1, 1);
    __syncthreads();
    f32x4 carry[4] = {};
    bd_chunk(0, carry);
    __syncthreads();

    for (int t = 0; t < 16; ++t) {
        const int p = t & 1;
        const int k0 = t * 64;

        // prefetch next K tile + P chunk (drained by this iter's end barrier)
        if (t < 15) { stage_k(t + 1, p ^ 1); stage_p(t + 2, p); }

        // V fragments direct from global (L2-hot, used at PV)
        bf16x8 vfr[4][2];
        #pragma unroll
        for (int nt = 0; nt < 4; ++nt) {
            const u16* vp = vth + vtbase + (size_t)(nt * 16 + arow) * T_ + k0 + kseg * 8;
            vfr[nt][0] = *(const bf16x8*)vp;
            vfr[nt][1] = *(const bf16x8*)(vp + 32);
        }

        __builtin_amdgcn_s_setprio(1);
        f32x4 ac[4] = {};
        #pragma unroll
        for (int nt = 0; nt < 4; ++nt) {
            int kr = nt * 16 + arow;
            bf16x8 b0h = *(const bf16x8*)(&s_k[p][0][0][0] + swz8(kr, kseg * 8));
            bf16x8 b1h = *(const bf16x8*)(&s_k[p][0][0][0] + swz8(kr, 32 + kseg * 8));
            bf16x8 b0l = *(const bf16x8*)(&s_k[p][1][0][0] + swz8(kr, kseg * 8));
            bf16x8 b1l = *(const bf16x8*)(&s_k[p][1][0][0] + swz8(kr, 32 + kseg * 8));
            ac[nt] = MFMA16(quh[0], b0h, ac[nt]);
            ac[nt] = MFMA16(quh[1], b1h, ac[nt]);
            ac[nt] = MFMA16(quh[0], b0l, ac[nt]);
            ac[nt] = MFMA16(quh[1], b1l, ac[nt]);
            ac[nt] = MFMA16(qul[0], b0h, ac[nt]);
            ac[nt] = MFMA16(qul[1], b1h, ac[nt]);
        }
        f32x4 bdn[4] = {};
        bd_chunk(p ^ 1, bdn);       // window rows 64..127 (chunk t+1)
        __builtin_amdgcn_s_setprio(0);

        // ---- round A: scatter carry (window rows 0..63), gather jj<64 ----
        #pragma unroll
        for (int nb = 0; nb < 4; ++nb)
            #pragma unroll
            for (int r = 0; r < 4; ++r)
                s_bd[w * 16 + kseg * 4 + r][(nb * 16 + arow) ^ (kseg << 4)] = carry[nb][r];
        asm volatile("s_waitcnt lgkmcnt(0)" ::: "memory");
        __builtin_amdgcn_sched_barrier(0);

        float sm[4][4];
        #pragma unroll
        for (int nt = 0; nt < 4; ++nt)
            #pragma unroll
            for (int r = 0; r < 4; ++r) {
                int qld = w * 16 + kseg * 4 + r;
                int jj = nt * 16 + arow + 63 - qld;
                sm[nt][r] = ac[nt][r];
                if (jj < 64) sm[nt][r] += s_bd[qld][jj ^ (kseg << 4)];
            }
        asm volatile("s_waitcnt lgkmcnt(0)" ::: "memory");
        __builtin_amdgcn_sched_barrier(0);

        // ---- round B: scatter new chunk (window rows 64..127), gather jj>=64 ----
        #pragma unroll
        for (int nb = 0; nb < 4; ++nb)
            #pragma unroll
            for (int r = 0; r < 4; ++r)
                s_bd[w * 16 + kseg * 4 + r][(nb * 16 + arow) ^ (kseg << 4)] = bdn[nb][r];
        asm volatile("s_waitcnt lgkmcnt(0)" ::: "memory");
        __builtin_amdgcn_sched_barrier(0);

        #pragma unroll
        for (int nt = 0; nt < 4; ++nt)
            #pragma unroll
            for (int r = 0; r < 4; ++r) {
                int qld = w * 16 + kseg * 4 + r;
                int jj = nt * 16 + arow + 63 - qld;
                if (jj >= 64) sm[nt][r] += s_bd[qld][(jj - 64) ^ (kseg << 4)];
            }
        asm volatile("s_waitcnt lgkmcnt(0)" ::: "memory");
        __builtin_amdgcn_sched_barrier(0);

        // ---- online softmax; P -> ppw (this wave's overlay region) ----
        #pragma unroll
        for (int r = 0; r < 4; ++r) {
            float mxv = fmaxf(fmaxf(sm[0][r], sm[1][r]), fmaxf(sm[2][r], sm[3][r]));
            #pragma unroll
            for (int off = 8; off; off >>= 1) mxv = fmaxf(mxv, __shfl_xor(mxv, off));
            float mnew = fmaxf(m_run[r], mxv);
            float fac = __expf(m_run[r] - mnew);
            m_run[r] = mnew;
            float ps = 0.f;
            int r16 = kseg * 4 + r;
            #pragma unroll
            for (int nt = 0; nt < 4; ++nt) {
                float pv = __expf(sm[nt][r] - mnew);
                ps += pv;
                int kl = nt * 16 + arow;
                ppw[r16 * 64 + ((((kl >> 3) ^ (r16 & 7)) << 3) | (kl & 7))] = f2bf(pv);
            }
            #pragma unroll
            for (int off = 8; off; off >>= 1) ps += __shfl_xor(ps, off);
            l_run[r] = l_run[r] * fac + ps;
            #pragma unroll
            for (int nt = 0; nt < 4; ++nt) o_[nt][r] *= fac;
        }
        asm volatile("s_waitcnt lgkmcnt(0)" ::: "memory");
        __builtin_amdgcn_sched_barrier(0);

        // ---- PV ----
        bf16x8 pa0 = *(const bf16x8*)(ppw + arow * 64 + ((kseg ^ (arow & 7)) << 3));
        bf16x8 pa1 = *(const bf16x8*)(ppw + arow * 64 + (((4 + kseg) ^ (arow & 7)) << 3));
        __builtin_amdgcn_s_setprio(1);
        #pragma unroll
        for (int nt = 0; nt < 4; ++nt) {
            o_[nt] = MFMA16(pa0, vfr[nt][0], o_[nt]);
            o_[nt] = MFMA16(pa1, vfr[nt][1], o_[nt]);
        }
        __builtin_amdgcn_s_setprio(0);

        #pragma unroll
        for (int nb = 0; nb < 4; ++nb) carry[nb] = bdn[nb];

        __syncthreads();   // drains vmcnt: prefetched K/P landed; LDS safe
    }

    // ---- epilogue ----
    #pragma unroll
    for (int nt = 0; nt < 4; ++nt)
        #pragma unroll
        for (int r = 0; r < 4; ++r) {
            int qrow = q0 + w * 16 + kseg * 4 + r;
            float val = o_[nt][r] / l_run[r];
            u16 hh, ll; splitbf(val, hh, ll);
            size_t off = ((size_t)(b * T_ + qrow)) * D_ + h * DK_ + nt * 16 + arow;
            aoh[off] = hh; aol[off] = ll;
        }
}

// ---------------------------------------------------------------------------
extern "C" void kernel_launch(void* const* d_in, const int* in_sizes, int n_in,
                              void* d_out, int out_size, void* d_ws, size_t ws_size,
                              hipStream_t stream)
{
    const float* q   = (const float*)d_in[0];
    const float* k   = (const float*)d_in[1];
    const float* v   = (const float*)d_in[2];
    const float* pe  = (const float*)d_in[3];
    const float* Wq  = (const float*)d_in[4];
    const float* bq  = (const float*)d_in[5];
    const float* Wk  = (const float*)d_in[6];
    const float* bk  = (const float*)d_in[7];
    const float* Wv  = (const float*)d_in[8];
    const float* bv  = (const float*)d_in[9];
    const float* Wp  = (const float*)d_in[10];
    const float* pbu = (const float*)d_in[11];
    const float* pbv = (const float*)d_in[12];
    const float* Wo  = (const float*)d_in[13];
    const float* bo  = (const float*)d_in[14];
    float* out = (float*)d_out;

    char* ws = (char*)d_ws;
    const size_t MB = 1024 * 1024;
    // region A (0-8MB): q split; later kh split (head-major)
    u16* qsh = (u16*)(ws);            u16* qsl = (u16*)(ws + 4 * MB);
    u16* khh = (u16*)(ws);            u16* khl = (u16*)(ws + 4 * MB);
    // region B (8-16MB): k split; later vt (4MB) + ph split (2+2MB)
    u16* ksh = (u16*)(ws + 8 * MB);   u16* ksl = (u16*)(ws + 12 * MB);
    u16* vth = (u16*)(ws + 8 * MB);
    u16* phh = (u16*)(ws + 12 * MB);  u16* phl = (u16*)(ws + 14 * MB);
    // region C (16-24MB): v split; later ao split
    u16* vsh = (u16*)(ws + 16 * MB);  u16* vsl = (u16*)(ws + 20 * MB);
    u16* aoh = (u16*)(ws + 16 * MB);  u16* aol = (u16*)(ws + 20 * MB);
    // region D (24-28MB): pe split
    u16* pesh = (u16*)(ws + 24 * MB); u16* pesl = (u16*)(ws + 26 * MB);
    // region E (28-33MB): weights split
    u16* wqh = (u16*)(ws + 28 * MB);  u16* wql = (u16*)(ws + 28 * MB + 512 * 1024);
    u16* wkh = (u16*)(ws + 29 * MB);  u16* wkl = (u16*)(ws + 29 * MB + 512 * 1024);
    u16* wvh = (u16*)(ws + 30 * MB);  u16* wvl = (u16*)(ws + 30 * MB + 512 * 1024);
    u16* wph = (u16*)(ws + 31 * MB);  u16* wpl = (u16*)(ws + 31 * MB + 512 * 1024);
    u16* woh = (u16*)(ws + 32 * MB);  u16* wol = (u16*)(ws + 32 * MB + 512 * 1024);
    // region F (33-41MB): qh fp32
    float* qh = (float*)(ws + 33 * MB);

    dim3 blk(256);
    conv_all<<<dim3(2048), blk, 0, stream>>>(q, k, v, pe, Wq, Wk, Wv, Wp, Wo,
        qsh, qsl, ksh, ksl, vsh, vsl, pesh, pesl,
        wqh, wql, wkh, wkl, wvh, wvl, wph, wpl, woh, wol);

    gemm_qkvp<<<dim3(8, 112), blk, 0, stream>>>(
        qsh, qsl, ksh, ksl, vsh, vsl, pesh, pesl,
        wqh, wql, wkh, wkl, wvh, wvl, wph, wpl,
        bq, bk, bv, qh, khh, khl, vth, phh, phl);

    relattn_mfma<<<dim3(512), blk, 0, stream>>>(qh, khh, khl, vth, phh, phl,
                                                pbu, pbv, aoh, aol);

    gemm_out<<<dim3(8, 32), blk, 0, stream>>>(aoh, aol, woh, wol, bo, out);
}

// Round 6
// 145.802 us; speedup vs baseline: 10.6455x; 1.0528x over previous
//
#include <hip/hip_runtime.h>
#include <math.h>

typedef unsigned short u16;
typedef __attribute__((ext_vector_type(8))) short bf16x8;
typedef __attribute__((ext_vector_type(4))) float f32x4;

#define B_  4
#define T_  1024
#define D_  512
#define H_  8
#define DK_ 64
#define P_  2047

#define MFMA16(a, b, c) __builtin_amdgcn_mfma_f32_16x16x32_bf16(a, b, c, 0, 0, 0)

__device__ __forceinline__ u16 f2bf(float x) {
    union { float f; unsigned u; } c; c.f = x;
    unsigned r = c.u + 0x7FFFu + ((c.u >> 16) & 1u);
    return (u16)(r >> 16);
}
__device__ __forceinline__ void splitbf(float x, u16& h, u16& l) {
    h = f2bf(x);
    union { unsigned u; float f; } hb; hb.u = ((unsigned)h) << 16;
    l = f2bf(x - hb.f);
}

__device__ __forceinline__ void gload_lds16(const u16* g, u16* l) {
    __builtin_amdgcn_global_load_lds(
        (const __attribute__((address_space(1))) void*)g,
        (__attribute__((address_space(3))) void*)l, 16, 0, 0);
}

__device__ __forceinline__ int swz8(int row, int colbase) {   // colbase % 8 == 0
    return row * 64 + (((colbase >> 3) ^ (row & 7)) << 3);
}

// ---------------------------------------------------------------------------
// One-shot conversion: inputs q,k,v,pe and 5 weights -> split bf16 planes.
// ---------------------------------------------------------------------------
__global__ __launch_bounds__(256)
void conv_all(const float* __restrict__ q, const float* __restrict__ k,
              const float* __restrict__ v, const float* __restrict__ pe,
              const float* __restrict__ wq, const float* __restrict__ wk,
              const float* __restrict__ wv, const float* __restrict__ wp,
              const float* __restrict__ wo,
              u16* qsh, u16* qsl, u16* ksh, u16* ksl, u16* vsh, u16* vsl,
              u16* pesh, u16* pesl,
              u16* wqh, u16* wql, u16* wkh, u16* wkl, u16* wvh, u16* wvl,
              u16* wph, u16* wpl, u16* woh, u16* wol)
{
    const int NQ = 524288;     // float4 chunks in q/k/v
    const int NPE = 262016;    // 2047*512/4
    const int NW = 65536;      // 512*512/4
    const int TOT = 3 * NQ + NPE + 5 * NW;
    for (int i = blockIdx.x * 256 + threadIdx.x; i < TOT; i += gridDim.x * 256) {
        const float* src; u16 *dh, *dl; int off;
        int j = i;
        if (j < NQ)              { src = q;  dh = qsh;  dl = qsl;  off = j; }
        else if ((j -= NQ) < NQ) { src = k;  dh = ksh;  dl = ksl;  off = j; }
        else if ((j -= NQ) < NQ) { src = v;  dh = vsh;  dl = vsl;  off = j; }
        else if ((j -= NQ) < NPE){ src = pe; dh = pesh; dl = pesl; off = j; }
        else if ((j -= NPE) < NW){ src = wq; dh = wqh;  dl = wql;  off = j; }
        else if ((j -= NW) < NW) { src = wk; dh = wkh;  dl = wkl;  off = j; }
        else if ((j -= NW) < NW) { src = wv; dh = wvh;  dl = wvl;  off = j; }
        else if ((j -= NW) < NW) { src = wp; dh = wph;  dl = wpl;  off = j; }
        else                     { j -= NW; src = wo; dh = woh; dl = wol; off = j; }
        float4 x = *(const float4*)(src + (size_t)off * 4);
        u16 hs[4], ls[4];
        splitbf(x.x, hs[0], ls[0]); splitbf(x.y, hs[1], ls[1]);
        splitbf(x.z, hs[2], ls[2]); splitbf(x.w, hs[3], ls[3]);
        *(uint2*)(dh + (size_t)off * 4) = *(uint2*)hs;
        *(uint2*)(dl + (size_t)off * 4) = *(uint2*)ls;
    }
}

// ---------------------------------------------------------------------------
// Shared GEMM core (validated). C = A[M,512] @ W[512,512]^T, split-bf16
// 3-term, BM=128 BN=64 BK=64.
// ---------------------------------------------------------------------------
__device__ __forceinline__ void gemm_core(
    const u16* __restrict__ Ah, const u16* __restrict__ Al,
    const u16* __restrict__ Bh, const u16* __restrict__ Bl,
    int bm, int bn, int M, f32x4 (&acc)[4][2],
    u16 (&sA)[2][128][64], u16 (&sB)[2][64][64])
{
    const int tid = threadIdx.x;
    const int ln = tid & 63, w = tid >> 6;
    const int arow = ln & 15, kseg = ln >> 4;
    const int wr = w >> 1, wc = w & 1;

    for (int k0 = 0; k0 < 512; k0 += 64) {
        #pragma unroll
        for (int pl = 0; pl < 2; ++pl) {
            const u16* As = pl ? Al : Ah;
            #pragma unroll
            for (int it = 0; it < 4; ++it) {
                int ch = it * 256 + tid;
                int r = ch >> 3, j = ch & 7;
                int rm = bm + r; if (rm > M - 1) rm = M - 1;
                gload_lds16(As + (size_t)rm * 512 + k0 + ((j ^ (r & 7)) << 3),
                            &sA[pl][0][0] + ch * 8);
            }
            const u16* Bs = pl ? Bl : Bh;
            #pragma unroll
            for (int it = 0; it < 2; ++it) {
                int ch = it * 256 + tid;
                int r = ch >> 3, j = ch & 7;
                gload_lds16(Bs + (size_t)(bn + r) * 512 + k0 + ((j ^ (r & 7)) << 3),
                            &sB[pl][0][0] + ch * 8);
            }
        }
        __syncthreads();

        bf16x8 af[2][4][2];
        bf16x8 bf[2][2][2];
        #pragma unroll
        for (int pl = 0; pl < 2; ++pl) {
            #pragma unroll
            for (int mi = 0; mi < 4; ++mi) {
                int row = wr * 64 + mi * 16 + arow;
                #pragma unroll
                for (int kc = 0; kc < 2; ++kc)
                    af[pl][mi][kc] = *(const bf16x8*)
                        (&sA[pl][row][0] + ((((kc << 2) | kseg) ^ (row & 7)) << 3));
            }
            #pragma unroll
            for (int nj = 0; nj < 2; ++nj) {
                int row = wc * 32 + nj * 16 + arow;
                #pragma unroll
                for (int kc = 0; kc < 2; ++kc)
                    bf[pl][nj][kc] = *(const bf16x8*)
                        (&sB[pl][row][0] + ((((kc << 2) | kseg) ^ (row & 7)) << 3));
            }
        }
        #pragma unroll
        for (int mi = 0; mi < 4; ++mi)
            #pragma unroll
            for (int nj = 0; nj < 2; ++nj)
                #pragma unroll
                for (int kc = 0; kc < 2; ++kc) {
                    acc[mi][nj] = MFMA16(af[0][mi][kc], bf[0][nj][kc], acc[mi][nj]);
                    acc[mi][nj] = MFMA16(af[0][mi][kc], bf[1][nj][kc], acc[mi][nj]);
                    acc[mi][nj] = MFMA16(af[1][mi][kc], bf[0][nj][kc], acc[mi][nj]);
                }
        __syncthreads();
    }
}

// ---------------------------------------------------------------------------
// Merged projection GEMM: q/k/v/pe in one launch. grid = (8, 112).
// ---------------------------------------------------------------------------
__global__ __launch_bounds__(256, 2)
void gemm_qkvp(const u16* __restrict__ qsh, const u16* __restrict__ qsl,
               const u16* __restrict__ ksh, const u16* __restrict__ ksl,
               const u16* __restrict__ vsh, const u16* __restrict__ vsl,
               const u16* __restrict__ pesh, const u16* __restrict__ pesl,
               const u16* __restrict__ wqh, const u16* __restrict__ wql,
               const u16* __restrict__ wkh, const u16* __restrict__ wkl,
               const u16* __restrict__ wvh, const u16* __restrict__ wvl,
               const u16* __restrict__ wph, const u16* __restrict__ wpl,
               const float* __restrict__ bq, const float* __restrict__ bk,
               const float* __restrict__ bv,
               float* __restrict__ qh, u16* __restrict__ khh, u16* __restrict__ khl,
               u16* __restrict__ vth, u16* __restrict__ phh, u16* __restrict__ phl)
{
    __shared__ u16 sA[2][128][64];
    __shared__ u16 sB[2][64][64];

    const int by = blockIdx.y;
    const u16 *Ah, *Al, *Bh, *Bl; const float* bias;
    int seg, bm, M, Tn;
    if (by < 32)      { seg=0; bm=by*128;       Ah=qsh;  Al=qsl;  Bh=wqh; Bl=wql; bias=bq;      M=4096; Tn=T_; }
    else if (by < 64) { seg=1; bm=(by-32)*128;  Ah=ksh;  Al=ksl;  Bh=wkh; Bl=wkl; bias=bk;      M=4096; Tn=T_; }
    else if (by < 96) { seg=2; bm=(by-64)*128;  Ah=vsh;  Al=vsl;  Bh=wvh; Bl=wvl; bias=bv;      M=4096; Tn=T_; }
    else              { seg=3; bm=(by-96)*128;  Ah=pesh; Al=pesl; Bh=wph; Bl=wpl; bias=nullptr; M=P_;   Tn=P_; }
    const int bn = blockIdx.x * 64;

    f32x4 acc[4][2] = {};
    gemm_core(Ah, Al, Bh, Bl, bm, bn, M, acc, sA, sB);

    const int tid = threadIdx.x;
    const int ln = tid & 63, w = tid >> 6;
    const int arow = ln & 15, kseg = ln >> 4;
    const int wr = w >> 1, wc = w & 1;

    float bv0[2];
    #pragma unroll
    for (int nj = 0; nj < 2; ++nj)
        bv0[nj] = bias ? bias[bn + wc * 32 + nj * 16 + arow] : 0.f;

    #pragma unroll
    for (int mi = 0; mi < 4; ++mi)
        #pragma unroll
        for (int r = 0; r < 4; ++r) {
            int m = bm + wr * 64 + mi * 16 + kseg * 4 + r;
            if (m >= M) continue;
            #pragma unroll
            for (int nj = 0; nj < 2; ++nj) {
                int n = bn + wc * 32 + nj * 16 + arow;
                float val = acc[mi][nj][r] + bv0[nj];
                if (seg == 0) {
                    qh[(size_t)m * 512 + n] = val;
                } else if (seg == 2) {
                    int bb = m >> 10, t = m & 1023;
                    int hh = n >> 6, d = n & 63;
                    vth[((size_t)(bb * H_ + hh) * 64 + d) * T_ + t] = f2bf(val);
                } else {
                    int bb = (Tn == T_) ? (m >> 10) : 0;
                    int t = m - bb * Tn;
                    int hh = n >> 6, d = n & 63;
                    size_t off = ((size_t)(bb * H_ + hh) * Tn + t) * 64 + d;
                    u16 h2, l2; splitbf(val, h2, l2);
                    if (seg == 1) { khh[off] = h2; khl[off] = l2; }
                    else          { phh[off] = h2; phl[off] = l2; }
                }
            }
        }
}

// ---------------------------------------------------------------------------
// Output projection (fp32 out)
// ---------------------------------------------------------------------------
__global__ __launch_bounds__(256, 2)
void gemm_out(const u16* __restrict__ Ah, const u16* __restrict__ Al,
              const u16* __restrict__ Bh, const u16* __restrict__ Bl,
              const float* __restrict__ bias, float* __restrict__ C)
{
    __shared__ u16 sA[2][128][64];
    __shared__ u16 sB[2][64][64];
    const int bn = blockIdx.x * 64;
    const int bm = blockIdx.y * 128;
    f32x4 acc[4][2] = {};
    gemm_core(Ah, Al, Bh, Bl, bm, bn, 4096, acc, sA, sB);

    const int tid = threadIdx.x;
    const int ln = tid & 63, w = tid >> 6;
    const int arow = ln & 15, kseg = ln >> 4;
    const int wr = w >> 1, wc = w & 1;
    #pragma unroll
    for (int mi = 0; mi < 4; ++mi)
        #pragma unroll
        for (int r = 0; r < 4; ++r) {
            int m = bm + wr * 64 + mi * 16 + kseg * 4 + r;
            #pragma unroll
            for (int nj = 0; nj < 2; ++nj) {
                int n = bn + wc * 32 + nj * 16 + arow;
                C[(size_t)m * 512 + n] = acc[mi][nj][r] + bias[n];
            }
        }
}

// ---------------------------------------------------------------------------
// Fused relative-position attention. Shift gather is now a pure in-wave
// shuffle (no LDS round-trip): for target (kseg,arow,nt,r),
//   jj = nt*16+arow+s,  s = 63-16w-4kseg-r = 16(3-w) + (15-4kseg-r)
// so the window register offset 3-w is WAVE-UNIFORM; per-lane only the
// rotation sl=15-4kseg-r and carry cy=(arow+sl)>>4 remain.
// One lgkmcnt drain left (P transpose for PV); one barrier per iter.
// ---------------------------------------------------------------------------
__global__ __launch_bounds__(256, 2)
void relattn_mfma(const float* __restrict__ qh,
                  const u16* __restrict__ khh, const u16* __restrict__ khl,
                  const u16* __restrict__ vth,
                  const u16* __restrict__ phh, const u16* __restrict__ phl,
                  const float* __restrict__ pbu, const float* __restrict__ pbv,
                  u16* __restrict__ aoh, u16* __restrict__ aol)
{
    __shared__ u16 s_k[2][2][64][64];   // [buf][plane][k][d]   32 KB
    __shared__ u16 s_p[2][2][64][64];   // [slot][plane][j][d]  32 KB (ring)
    __shared__ u16 s_pp[4][16][64];     // wave-private P tiles  8 KB

    const int tid = threadIdx.x;
    const int ln  = tid & 63;
    const int w   = tid >> 6;
    const int arow = ln & 15;
    const int kseg = ln >> 4;

    // XCD swizzle: each XCD gets 4 whole (b,h) groups
    const int lg = ((blockIdx.x & 7) << 6) | (blockIdx.x >> 3);
    const int qt = lg & 15, h = (lg >> 4) & 7, b = lg >> 7;
    const int q0 = qt * 64;

    // ---- Q fragments (scaled 1/8, +u/+v, split hi/lo) ----
    bf16x8 quh[2], qul[2], qvh[2], qvl[2];
    #pragma unroll
    for (int c = 0; c < 2; ++c) {
        const float* qp = qh + ((size_t)(b * T_ + q0 + w * 16 + arow)) * D_ + h * DK_ + c * 32 + kseg * 8;
        float4 a0 = *(const float4*)qp;
        float4 a1 = *(const float4*)(qp + 4);
        const float* up = pbu + h * DK_ + c * 32 + kseg * 8;
        const float* vp = pbv + h * DK_ + c * 32 + kseg * 8;
        float4 u0 = *(const float4*)up, u1 = *(const float4*)(up + 4);
        float4 v0 = *(const float4*)vp, v1 = *(const float4*)(vp + 4);
        float qa[8] = {a0.x, a0.y, a0.z, a0.w, a1.x, a1.y, a1.z, a1.w};
        float ua[8] = {u0.x, u0.y, u0.z, u0.w, u1.x, u1.y, u1.z, u1.w};
        float va[8] = {v0.x, v0.y, v0.z, v0.w, v1.x, v1.y, v1.z, v1.w};
        #pragma unroll
        for (int i = 0; i < 8; ++i) {
            u16 hh2, ll2;
            splitbf((qa[i] + ua[i]) * 0.125f, hh2, ll2);
            quh[c][i] = (short)hh2; qul[c][i] = (short)ll2;
            splitbf((qa[i] + va[i]) * 0.125f, hh2, ll2);
            qvh[c][i] = (short)hh2; qvl[c][i] = (short)ll2;
        }
    }

    f32x4 o_[4] = {};
    float m_run[4] = {-1e30f, -1e30f, -1e30f, -1e30f};
    float l_run[4] = {};

    const size_t kvbase = (size_t)(b * H_ + h) * T_ * 64;
    const size_t vtbase = (size_t)(b * H_ + h) * 64 * T_;
    const size_t pbase  = (size_t)h * P_ * 64;
    const int jb0 = 960 - q0;                 // j of chunk 0 row 0

    auto stage_k = [&](int kt, int buf) {
        #pragma unroll
        for (int it = 0; it < 4; ++it) {
            int idx = tid + it * 256;
            int pl = idx >> 9, r = (idx >> 3) & 63, ch = idx & 7;
            const u16* src = (pl ? khl : khh) + kvbase + (size_t)(kt * 64 + r) * 64 + ((ch ^ (r & 7)) << 3);
            gload_lds16(src, &s_k[buf][0][0][0] + idx * 8);
        }
    };
    auto stage_p = [&](int c, int slot) {
        #pragma unroll
        for (int it = 0; it < 4; ++it) {
            int idx = tid + it * 256;
            int pl = idx >> 9, r = (idx >> 3) & 63, ch = idx & 7;
            int j = jb0 + c * 64 + r; if (j > P_ - 1) j = P_ - 1;
            const u16* src = (pl ? phl : phh) + pbase + (size_t)j * 64 + ((ch ^ (r & 7)) << 3);
            gload_lds16(src, &s_p[slot][0][0][0] + idx * 8);
        }
    };
    auto bd_chunk = [&](int slot, f32x4* out) {
        #pragma unroll
        for (int nb = 0; nb < 4; ++nb) {
            int pr = nb * 16 + arow;
            bf16x8 b0h = *(const bf16x8*)(&s_p[slot][0][0][0] + swz8(pr, kseg * 8));
            bf16x8 b1h = *(const bf16x8*)(&s_p[slot][0][0][0] + swz8(pr, 32 + kseg * 8));
            bf16x8 b0l = *(const bf16x8*)(&s_p[slot][1][0][0] + swz8(pr, kseg * 8));
            bf16x8 b1l = *(const bf16x8*)(&s_p[slot][1][0][0] + swz8(pr, 32 + kseg * 8));
            out[nb] = MFMA16(qvh[0], b0h, out[nb]);
            out[nb] = MFMA16(qvh[1], b1h, out[nb]);
            out[nb] = MFMA16(qvh[0], b0l, out[nb]);
            out[nb] = MFMA16(qvh[1], b1l, out[nb]);
            out[nb] = MFMA16(qvl[0], b0h, out[nb]);
            out[nb] = MFMA16(qvl[1], b1h, out[nb]);
        }
    };

    // ---- prologue ----
    stage_k(0, 0); stage_p(0, 0); stage_p(1, 1);
    __syncthreads();
    f32x4 carry[4] = {};
    bd_chunk(0, carry);
    __syncthreads();

    for (int t = 0; t < 16; ++t) {
        const int p = t & 1;
        const int k0 = t * 64;

        // prefetch next K tile + P chunk (land by this iter's end barrier)
        if (t < 15) { stage_k(t + 1, p ^ 1); stage_p(t + 2, p); }

        // V fragments direct from global (used at PV)
        bf16x8 vfr[4][2];
        #pragma unroll
        for (int nt = 0; nt < 4; ++nt) {
            const u16* vp = vth + vtbase + (size_t)(nt * 16 + arow) * T_ + k0 + kseg * 8;
            vfr[nt][0] = *(const bf16x8*)vp;
            vfr[nt][1] = *(const bf16x8*)(vp + 32);
        }

        __builtin_amdgcn_s_setprio(1);
        f32x4 ac[4] = {};
        #pragma unroll
        for (int nt = 0; nt < 4; ++nt) {
            int kr = nt * 16 + arow;
            bf16x8 b0h = *(const bf16x8*)(&s_k[p][0][0][0] + swz8(kr, kseg * 8));
            bf16x8 b1h = *(const bf16x8*)(&s_k[p][0][0][0] + swz8(kr, 32 + kseg * 8));
            bf16x8 b0l = *(const bf16x8*)(&s_k[p][1][0][0] + swz8(kr, kseg * 8));
            bf16x8 b1l = *(const bf16x8*)(&s_k[p][1][0][0] + swz8(kr, 32 + kseg * 8));
            ac[nt] = MFMA16(quh[0], b0h, ac[nt]);
            ac[nt] = MFMA16(quh[1], b1h, ac[nt]);
            ac[nt] = MFMA16(quh[0], b0l, ac[nt]);
            ac[nt] = MFMA16(quh[1], b1l, ac[nt]);
            ac[nt] = MFMA16(qul[0], b0h, ac[nt]);
            ac[nt] = MFMA16(qul[1], b1h, ac[nt]);
        }
        f32x4 bdn[4] = {};
        bd_chunk(p ^ 1, bdn);       // window rows 64..127 (chunk t+1)
        __builtin_amdgcn_s_setprio(0);

        // ---- shift gather: pure in-wave shuffle ----
        // window regs BDsel[c]: c<4 -> carry[c] (rows c*16+arow),
        //                       c>=4 -> bdn[c-4] (rows c*16+arow)
        // need BDsel[(3-w) .. (7-w)] -> win[0..4]  (wave-uniform branch)
        float win[5][4];
        #pragma unroll
        for (int r = 0; r < 4; ++r) {
            if (w == 0)      { win[0][r]=carry[3][r]; win[1][r]=bdn[0][r];   win[2][r]=bdn[1][r];   win[3][r]=bdn[2][r];   win[4][r]=bdn[3][r]; }
            else if (w == 1) { win[0][r]=carry[2][r]; win[1][r]=carry[3][r]; win[2][r]=bdn[0][r];   win[3][r]=bdn[1][r];   win[4][r]=bdn[2][r]; }
            else if (w == 2) { win[0][r]=carry[1][r]; win[1][r]=carry[2][r]; win[2][r]=carry[3][r]; win[3][r]=bdn[0][r];   win[4][r]=bdn[1][r]; }
            else             { win[0][r]=carry[0][r]; win[1][r]=carry[1][r]; win[2][r]=carry[2][r]; win[3][r]=carry[3][r]; win[4][r]=bdn[0][r]; }
        }

        float sm[4][4];
        #pragma unroll
        for (int r = 0; r < 4; ++r) {
            int sl  = 15 - (kseg << 2) - r;              // s & 15 (per-lane)
            int src = (ln & 48) | ((arow + sl) & 15);    // same 16-lane group
            int cy  = (arow + sl) >> 4;                  // 0/1 chunk carry
            float pm[5];
            #pragma unroll
            for (int i = 0; i < 5; ++i) pm[i] = __shfl(win[i][r], src, 64);
            #pragma unroll
            for (int nt = 0; nt < 4; ++nt)
                sm[nt][r] = ac[nt][r] + (cy ? pm[nt + 1] : pm[nt]);
        }

        // ---- online softmax; P -> s_pp[w] (wave-private) ----
        #pragma unroll
        for (int r = 0; r < 4; ++r) {
            float mxv = fmaxf(fmaxf(sm[0][r], sm[1][r]), fmaxf(sm[2][r], sm[3][r]));
            #pragma unroll
            for (int off = 8; off; off >>= 1) mxv = fmaxf(mxv, __shfl_xor(mxv, off));
            float mnew = fmaxf(m_run[r], mxv);
            float fac = __expf(m_run[r] - mnew);
            m_run[r] = mnew;
            float ps = 0.f;
            int r16 = kseg * 4 + r;
            #pragma unroll
            for (int nt = 0; nt < 4; ++nt) {
                float pv = __expf(sm[nt][r] - mnew);
                ps += pv;
                int kl = nt * 16 + arow;
                s_pp[w][r16][(((kl >> 3) ^ (r16 & 7)) << 3) | (kl & 7)] = f2bf(pv);
            }
            #pragma unroll
            for (int off = 8; off; off >>= 1) ps += __shfl_xor(ps, off);
            l_run[r] = l_run[r] * fac + ps;
            #pragma unroll
            for (int nt = 0; nt < 4; ++nt) o_[nt][r] *= fac;
        }
        asm volatile("s_waitcnt lgkmcnt(0)" ::: "memory");
        __builtin_amdgcn_sched_barrier(0);

        // ---- PV ----
        bf16x8 pa0 = *(const bf16x8*)(&s_pp[w][arow][0] + ((kseg ^ (arow & 7)) << 3));
        bf16x8 pa1 = *(const bf16x8*)(&s_pp[w][arow][0] + (((4 + kseg) ^ (arow & 7)) << 3));
        __builtin_amdgcn_s_setprio(1);
        #pragma unroll
        for (int nt = 0; nt < 4; ++nt) {
            o_[nt] = MFMA16(pa0, vfr[nt][0], o_[nt]);
            o_[nt] = MFMA16(pa1, vfr[nt][1], o_[nt]);
        }
        __builtin_amdgcn_s_setprio(0);

        #pragma unroll
        for (int nb = 0; nb < 4; ++nb) carry[nb] = bdn[nb];

        __syncthreads();   // publish prefetched K/P; protect s_pp reuse
    }

    // ---- epilogue ----
    #pragma unroll
    for (int nt = 0; nt < 4; ++nt)
        #pragma unroll
        for (int r = 0; r < 4; ++r) {
            int qrow = q0 + w * 16 + kseg * 4 + r;
            float val = o_[nt][r] / l_run[r];
            u16 hh, ll; splitbf(val, hh, ll);
            size_t off = ((size_t)(b * T_ + qrow)) * D_ + h * DK_ + nt * 16 + arow;
            aoh[off] = hh; aol[off] = ll;
        }
}

// ---------------------------------------------------------------------------
extern "C" void kernel_launch(void* const* d_in, const int* in_sizes, int n_in,
                              void* d_out, int out_size, void* d_ws, size_t ws_size,
                              hipStream_t stream)
{
    const float* q   = (const float*)d_in[0];
    const float* k   = (const float*)d_in[1];
    const float* v   = (const float*)d_in[2];
    const float* pe  = (const float*)d_in[3];
    const float* Wq  = (const float*)d_in[4];
    const float* bq  = (const float*)d_in[5];
    const float* Wk  = (const float*)d_in[6];
    const float* bk  = (const float*)d_in[7];
    const float* Wv  = (const float*)d_in[8];
    const float* bv  = (const float*)d_in[9];
    const float* Wp  = (const float*)d_in[10];
    const float* pbu = (const float*)d_in[11];
    const float* pbv = (const float*)d_in[12];
    const float* Wo  = (const float*)d_in[13];
    const float* bo  = (const float*)d_in[14];
    float* out = (float*)d_out;

    char* ws = (char*)d_ws;
    const size_t MB = 1024 * 1024;
    u16* qsh = (u16*)(ws);            u16* qsl = (u16*)(ws + 4 * MB);
    u16* khh = (u16*)(ws);            u16* khl = (u16*)(ws + 4 * MB);
    u16* ksh = (u16*)(ws + 8 * MB);   u16* ksl = (u16*)(ws + 12 * MB);
    u16* vth = (u16*)(ws + 8 * MB);
    u16* phh = (u16*)(ws + 12 * MB);  u16* phl = (u16*)(ws + 14 * MB);
    u16* vsh = (u16*)(ws + 16 * MB);  u16* vsl = (u16*)(ws + 20 * MB);
    u16* aoh = (u16*)(ws + 16 * MB);  u16* aol = (u16*)(ws + 20 * MB);
    u16* pesh = (u16*)(ws + 24 * MB); u16* pesl = (u16*)(ws + 26 * MB);
    u16* wqh = (u16*)(ws + 28 * MB);  u16* wql = (u16*)(ws + 28 * MB + 512 * 1024);
    u16* wkh = (u16*)(ws + 29 * MB);  u16* wkl = (u16*)(ws + 29 * MB + 512 * 1024);
    u16* wvh = (u16*)(ws + 30 * MB);  u16* wvl = (u16*)(ws + 30 * MB + 512 * 1024);
    u16* wph = (u16*)(ws + 31 * MB);  u16* wpl = (u16*)(ws + 31 * MB + 512 * 1024);
    u16* woh = (u16*)(ws + 32 * MB);  u16* wol = (u16*)(ws + 32 * MB + 512 * 1024);
    float* qh = (float*)(ws + 33 * MB);

    dim3 blk(256);
    conv_all<<<dim3(2048), blk, 0, stream>>>(q, k, v, pe, Wq, Wk, Wv, Wp, Wo,
        qsh, qsl, ksh, ksl, vsh, vsl, pesh, pesl,
        wqh, wql, wkh, wkl, wvh, wvl, wph, wpl, woh, wol);

    gemm_qkvp<<<dim3(8, 112), blk, 0, stream>>>(
        qsh, qsl, ksh, ksl, vsh, vsl, pesh, pesl,
        wqh, wql, wkh, wkl, wvh, wvl, wph, wpl,
        bq, bk, bv, qh, khh, khl, vth, phh, phl);

    relattn_mfma<<<dim3(512), blk, 0, stream>>>(qh, khh, khl, vth, phh, phl,
                                                pbu, pbv, aoh, aol);

    gemm_out<<<dim3(8, 32), blk, 0, stream>>>(aoh, aol, woh, wol, bo, out);
}